// Round 6
// baseline (422.353 us; speedup 1.0000x reference)
//
#include <hip/hip_runtime.h>
#include <hip/hip_bf16.h>
#include <math.h>

// Problem constants (B=2,S=2048 -> T=4096 tokens)
#define T_TOKENS 4096
#define D_DIM 768
#define F_DIM 3072
#define E_NUM 8

#define BM 128
#define BN 128
#define BK 32
#define BNP 40                   // padded Bs row (elems): conflict-free writes+reads
#define RBMAX 72                 // max padded 128-row blocks
#define NBU (F_DIM / BN)         // 24
#define NBD (D_DIM / BN)         // 6
#define UP_BLOCKS (NBU * RBMAX)  // 1728
#define DBM 64                   // down-GEMM row-tile
#define DN_BLOCKS (NBD * RBMAX * 2)  // 864

typedef __attribute__((ext_vector_type(8))) short short8;
typedef __attribute__((ext_vector_type(4))) short short4v;
typedef __attribute__((ext_vector_type(4))) float float4v;
typedef unsigned short ushort_t;

__device__ __forceinline__ ushort_t f2bf(float f) {
    union { float f; unsigned u; } v; v.f = f;
    unsigned r = v.u + 0x7fffu + ((v.u >> 16) & 1u);   // RNE
    return (ushort_t)(r >> 16);
}

__device__ __forceinline__ float gelu_fast(float v) {
    float u = v + 0.044715f * v * v * v;
    return v / (1.f + __expf(-1.5957691216f * u));
}

#define GLOAD_LDS16(gp, lp) __builtin_amdgcn_global_load_lds( \
    (const __attribute__((address_space(1))) void*)(gp),      \
    (__attribute__((address_space(3))) void*)(lp), 16, 0, 0)

// ============================================================ prep: gate + x->bf16
#define PB_GATE 1024
#define PB_CVT 1024
#define P1_TOTAL (PB_GATE + PB_CVT)

__global__ void k_prep(const float* __restrict__ x, const float* __restrict__ gw,
                       int* __restrict__ counts, int* __restrict__ list,
                       float* __restrict__ wsel, ushort_t* __restrict__ xb) {
    int bid = blockIdx.x;
    if (bid < PB_GATE) {
        int wave = threadIdx.x >> 6, lane = threadIdx.x & 63;
        int t = bid * 4 + wave;
        float acc[E_NUM];
#pragma unroll
        for (int e = 0; e < E_NUM; ++e) acc[e] = 0.f;
        const float* xr = x + (size_t)t * D_DIM;
        for (int d = lane; d < D_DIM; d += 64) {
            float xv = xr[d];
            const float* g = gw + d * E_NUM;
#pragma unroll
            for (int e = 0; e < E_NUM; ++e) acc[e] += xv * g[e];
        }
#pragma unroll
        for (int e = 0; e < E_NUM; ++e) {
#pragma unroll
            for (int s = 32; s >= 1; s >>= 1) acc[e] += __shfl_xor(acc[e], s);
        }
        if (lane == 0) {
            float mx = acc[0];
#pragma unroll
            for (int e = 1; e < E_NUM; ++e) mx = fmaxf(mx, acc[e]);
            float p[E_NUM], sum = 0.f;
#pragma unroll
            for (int e = 0; e < E_NUM; ++e) { p[e] = expf(acc[e] - mx); sum += p[e]; }
            float inv = 1.f / sum;
#pragma unroll
            for (int e = 0; e < E_NUM; ++e) p[e] *= inv;
            int e1 = 0;
#pragma unroll
            for (int e = 1; e < E_NUM; ++e) if (p[e] > p[e1]) e1 = e;
            int e2 = (e1 == 0) ? 1 : 0;
#pragma unroll
            for (int e = 0; e < E_NUM; ++e) if (e != e1 && p[e] > p[e2]) e2 = e;
            int s1 = atomicAdd(&counts[e1], 1);
            list[e1 * T_TOKENS + s1] = t * 2 + 0;      // token | slot bit
            int s2 = atomicAdd(&counts[e2], 1);
            list[e2 * T_TOKENS + s2] = t * 2 + 1;
            wsel[t * 2 + 0] = p[e1];
            wsel[t * 2 + 1] = p[e2];
        }
        return;
    }
    bid -= PB_GATE;
    {   // x -> bf16
        int n4 = T_TOKENS * D_DIM / 4;
        for (int j = bid * 256 + threadIdx.x; j < n4; j += PB_CVT * 256) {
            float4v v = ((const float4v*)x)[j];
            unsigned long long o =
                (unsigned long long)f2bf(v[0]) |
                ((unsigned long long)f2bf(v[1]) << 16) |
                ((unsigned long long)f2bf(v[2]) << 32) |
                ((unsigned long long)f2bf(v[3]) << 48);
            ((unsigned long long*)xb)[j] = o;
        }
    }
}

// ---------------------------------------------------------------- finalize
__global__ void k_finalize(const int* __restrict__ counts, int* __restrict__ pcount,
                           int* __restrict__ offs, int* __restrict__ nrb,
                           int* __restrict__ rbmap) {
    if (threadIdx.x == 0) {
        int acc = 0, rb = 0;
        for (int e = 0; e < E_NUM; ++e) {
            int pc = (counts[e] + BM - 1) / BM * BM;
            pcount[e] = pc;
            offs[e] = acc;
            for (int i = 0; i < pc / BM; ++i) rbmap[rb++] = e;
            acc += pc;
        }
        nrb[0] = rb;
    }
}

// ---------------------------------------------------------------- compact
__global__ void k_compact(const int* __restrict__ counts, const int* __restrict__ pcount,
                          const int* __restrict__ offs, const int* __restrict__ list,
                          int* __restrict__ clist, int* __restrict__ rowOf) {
    int e = blockIdx.y;
    int s = blockIdx.x * 256 + threadIdx.x;
    if (s >= pcount[e]) return;
    int g = offs[e] + s;
    if (s < counts[e]) {
        int v = list[e * T_TOKENS + s];
        clist[g] = v >> 1;
        rowOf[v] = g;                 // v = tok*2 + slot
    } else {
        clist[g] = 0;                 // padding row gathers token 0 (output unused)
    }
}

// ---------------------------------------------------------------- up GEMM
// A: bf16 gathered rows via global_load_lds (XOR-swizzled source).
// B: native fp32 w_up [D][F] -> in-register cvt+transpose -> Bs[n][k] (padded).
__global__ void k_up_gemm(const ushort_t* __restrict__ xb, const float* __restrict__ wup,
                          const float* __restrict__ b_up, const int* __restrict__ nrb,
                          const int* __restrict__ rbmap, const int* __restrict__ clist,
                          ushort_t* __restrict__ h) {
    int wg = blockIdx.x;
    int lin = (wg & 7) * (UP_BLOCKS / 8) + (wg >> 3);
    int nb = lin / RBMAX;
    int rb = lin % RBMAX;
    if (rb >= nrb[0]) return;
    int e = rbmap[rb];
    __shared__ __align__(16) ushort_t As[2][BM][BK];
    __shared__ __align__(16) ushort_t Bs[2][BN][BNP];
    int t = threadIdx.x, wave = t >> 6, lane = t & 63;
    int wm = wave >> 1, wn = wave & 1;

    int row0 = rb * BM;
    int tokA0 = clist[row0 + (t >> 2)];
    int tokA1 = clist[row0 + 64 + (t >> 2)];

    float4v acc[4][4];
#pragma unroll
    for (int i = 0; i < 4; ++i)
#pragma unroll
        for (int j = 0; j < 4; ++j)
#pragma unroll
            for (int q = 0; q < 4; ++q) acc[i][j][q] = 0.f;

    int csw = (((t & 3) ^ ((t >> 3) & 3))) * 8;                 // A staged src chunk
    int swoff = (((lane >> 4) ^ (((lane & 15) >> 1) & 3))) * 8; // A read-side chunk

    const ushort_t* gA0 = xb + (size_t)tokA0 * D_DIM + csw;
    const ushort_t* gA1 = xb + (size_t)tokA1 * D_DIM + csw;

    // B staging geometry: thread covers 4k x 4n
    int bk0 = (lane & 7) * 4;                  // k within BK
    int bn0 = (wave * 8 + (lane >> 3)) * 4;    // n within BN
    const float* bBase = wup + (size_t)e * D_DIM * F_DIM + (size_t)bk0 * F_DIM
                         + nb * BN + bn0;
    float4v bv[4];

#define A_STAGE_UP(buf, kt) do { int k0 = (kt) * BK;                          \
        char* AsB = (char*)&As[buf][0][0];                                    \
        GLOAD_LDS16(gA0 + k0, AsB + wave * 1024);                             \
        GLOAD_LDS16(gA1 + k0, AsB + 4096 + wave * 1024); } while (0)
#define B_LOAD_UP(kt) do { const float* bp = bBase + (size_t)(kt) * BK * F_DIM; \
        bv[0] = *(const float4v*)(bp);                                        \
        bv[1] = *(const float4v*)(bp + F_DIM);                                \
        bv[2] = *(const float4v*)(bp + 2 * F_DIM);                            \
        bv[3] = *(const float4v*)(bp + 3 * F_DIM); } while (0)
#define B_WRITE(buf) do {                                                     \
        _Pragma("unroll")                                                     \
        for (int j = 0; j < 4; ++j) {                                         \
            short4v s = { (short)f2bf(bv[0][j]), (short)f2bf(bv[1][j]),       \
                          (short)f2bf(bv[2][j]), (short)f2bf(bv[3][j]) };     \
            *(short4v*)&Bs[buf][bn0 + j][bk0] = s;                            \
        } } while (0)

    A_STAGE_UP(0, 0);
    B_LOAD_UP(0);
    B_WRITE(0);
    __syncthreads();
    const int nt = D_DIM / BK;
    for (int kt = 0; kt < nt; ++kt) {
        int buf = kt & 1;
        if (kt + 1 < nt) { A_STAGE_UP(buf ^ 1, kt + 1); B_LOAD_UP(kt + 1); }
        short8 af[4], bfr[4];
#pragma unroll
        for (int m = 0; m < 4; ++m)
            af[m] = *(const short8*)&As[buf][wm * 64 + m * 16 + (lane & 15)][swoff];
#pragma unroll
        for (int n = 0; n < 4; ++n)
            bfr[n] = *(const short8*)&Bs[buf][wn * 64 + n * 16 + (lane & 15)][(lane >> 4) * 8];
#pragma unroll
        for (int m = 0; m < 4; ++m)
#pragma unroll
            for (int n = 0; n < 4; ++n)
                acc[m][n] = __builtin_amdgcn_mfma_f32_16x16x32_bf16(af[m], bfr[n], acc[m][n], 0, 0, 0);
        if (kt + 1 < nt) B_WRITE(buf ^ 1);
        __syncthreads();
    }

#pragma unroll
    for (int m = 0; m < 4; ++m) {
        int row_local = wm * 64 + m * 16 + (lane >> 4) * 4;
#pragma unroll
        for (int n = 0; n < 4; ++n) {
            int col = nb * BN + wn * 64 + n * 16 + (lane & 15);
            float bia = b_up[e * F_DIM + col];
#pragma unroll
            for (int j = 0; j < 4; ++j) {
                float v = acc[m][n][j] + bia;
                h[(size_t)(row0 + row_local + j) * F_DIM + col] = f2bf(gelu_fast(v));
            }
        }
    }
}

// ---------------------------------------------------------------- down GEMM
// A: h bf16 via global_load_lds (swizzled source). B: native fp32 w_down [F][D]
// in-register cvt+transpose. Plain fp32 stores to ybuf (bias folded).
__global__ void k_down_gemm(const ushort_t* __restrict__ h, const float* __restrict__ wdn,
                            const float* __restrict__ b_down, const int* __restrict__ nrb,
                            const int* __restrict__ rbmap, float* __restrict__ yb) {
    int wg = blockIdx.x;
    int lin = (wg & 7) * (DN_BLOCKS / 8) + (wg >> 3);
    int nb = lin / (RBMAX * 2);
    int rbD = lin % (RBMAX * 2);
    if ((rbD >> 1) >= nrb[0]) return;
    int e = rbmap[rbD >> 1];
    __shared__ __align__(16) ushort_t As[2][DBM][BK];
    __shared__ __align__(16) ushort_t Bs[2][BN][BNP];
    int t = threadIdx.x, wave = t >> 6, lane = t & 63;
    int wm = wave >> 1, wn = wave & 1;

    int row0 = rbD * DBM;
    const ushort_t* ha = h + (size_t)row0 * F_DIM;

    float4v acc[2][4];
#pragma unroll
    for (int i = 0; i < 2; ++i)
#pragma unroll
        for (int j = 0; j < 4; ++j)
#pragma unroll
            for (int q = 0; q < 4; ++q) acc[i][j][q] = 0.f;

    int csw = (((t & 3) ^ ((t >> 3) & 3))) * 8;
    int swoff = (((lane >> 4) ^ (((lane & 15) >> 1) & 3))) * 8;

    const ushort_t* gA0 = ha + (size_t)(t >> 2) * F_DIM + csw;

    int bk0 = (lane & 7) * 4;
    int bn0 = (wave * 8 + (lane >> 3)) * 4;
    const float* bBase = wdn + (size_t)e * F_DIM * D_DIM + (size_t)bk0 * D_DIM
                         + nb * BN + bn0;
    float4v bv[4];

#define A_STAGE_DN(buf, kt) do { int k0 = (kt) * BK;                          \
        char* AsB = (char*)&As[buf][0][0];                                    \
        GLOAD_LDS16(gA0 + k0, AsB + wave * 1024); } while (0)
#define B_LOAD_DN(kt) do { const float* bp = bBase + (size_t)(kt) * BK * D_DIM; \
        bv[0] = *(const float4v*)(bp);                                        \
        bv[1] = *(const float4v*)(bp + D_DIM);                                \
        bv[2] = *(const float4v*)(bp + 2 * D_DIM);                            \
        bv[3] = *(const float4v*)(bp + 3 * D_DIM); } while (0)

    A_STAGE_DN(0, 0);
    B_LOAD_DN(0);
    B_WRITE(0);
    __syncthreads();
    const int nt = F_DIM / BK;
    for (int kt = 0; kt < nt; ++kt) {
        int buf = kt & 1;
        if (kt + 1 < nt) { A_STAGE_DN(buf ^ 1, kt + 1); B_LOAD_DN(kt + 1); }
        short8 af[2], bfr[4];
#pragma unroll
        for (int m = 0; m < 2; ++m)
            af[m] = *(const short8*)&As[buf][wm * 32 + m * 16 + (lane & 15)][swoff];
#pragma unroll
        for (int n = 0; n < 4; ++n)
            bfr[n] = *(const short8*)&Bs[buf][wn * 64 + n * 16 + (lane & 15)][(lane >> 4) * 8];
#pragma unroll
        for (int m = 0; m < 2; ++m)
#pragma unroll
            for (int n = 0; n < 4; ++n)
                acc[m][n] = __builtin_amdgcn_mfma_f32_16x16x32_bf16(af[m], bfr[n], acc[m][n], 0, 0, 0);
        if (kt + 1 < nt) B_WRITE(buf ^ 1);
        __syncthreads();
    }

#pragma unroll
    for (int m = 0; m < 2; ++m) {
        int row_local = wm * 32 + m * 16 + (lane >> 4) * 4;
#pragma unroll
        for (int n = 0; n < 4; ++n) {
            int col = nb * BN + wn * 64 + n * 16 + (lane & 15);
            float bia = b_down[e * D_DIM + col];
#pragma unroll
            for (int j = 0; j < 4; ++j) {
                yb[(size_t)(row0 + row_local + j) * D_DIM + col] = acc[m][n][j] + bia;
            }
        }
    }
}

// ---------------------------------------------------------------- combine
__global__ void k_combine(const float* __restrict__ yb, const int* __restrict__ rowOf,
                          const float* __restrict__ wsel, float* __restrict__ out) {
    int wave = threadIdx.x >> 6, lane = threadIdx.x & 63;
    int t = blockIdx.x * 4 + wave;
    int g0 = rowOf[t * 2], g1 = rowOf[t * 2 + 1];
    float w0 = wsel[t * 2], w1 = wsel[t * 2 + 1];
    const float4v* y0 = (const float4v*)(yb + (size_t)g0 * D_DIM);
    const float4v* y1 = (const float4v*)(yb + (size_t)g1 * D_DIM);
    float4v* o = (float4v*)(out + (size_t)t * D_DIM);
#pragma unroll
    for (int i = 0; i < 3; ++i) {
        int idx = lane + i * 64;
        float4v a = y0[idx], b = y1[idx];
        float4v r;
#pragma unroll
        for (int q = 0; q < 4; ++q) r[q] = w0 * a[q] + w1 * b[q];
        o[idx] = r;
    }
}

// ---------------------------------------------------------------- launch
extern "C" void kernel_launch(void* const* d_in, const int* in_sizes, int n_in,
                              void* d_out, int out_size, void* d_ws, size_t ws_size,
                              hipStream_t stream) {
    const float* x   = (const float*)d_in[0];   // [2,2048,768]
    const float* gw  = (const float*)d_in[1];   // [768,8]
    const float* wup = (const float*)d_in[2];   // [8,768,3072]
    const float* bup = (const float*)d_in[3];   // [8,3072]
    const float* wdn = (const float*)d_in[4];   // [8,3072,768]
    const float* bdn = (const float*)d_in[5];   // [8,768]
    float* out = (float*)d_out;

    char* ws = (char*)d_ws;
    int*   counts = (int*)(ws);
    int*   pcount = (int*)(ws + 32);
    int*   offs   = (int*)(ws + 64);
    int*   nrb    = (int*)(ws + 96);
    int*   rbmap  = (int*)(ws + 128);
    int*   list   = (int*)(ws + 1024);
    size_t p = 1024 + (size_t)E_NUM * T_TOKENS * 4;
    int*   clist  = (int*)(ws + p); p += (size_t)(RBMAX * BM) * 4;
    int*   rowOf  = (int*)(ws + p); p += (size_t)T_TOKENS * 2 * 4;
    float* wsel   = (float*)(ws + p); p += (size_t)T_TOKENS * 2 * 4;
    p = (p + 255) & ~(size_t)255;
    ushort_t* xb   = (ushort_t*)(ws + p); p += (size_t)T_TOKENS * D_DIM * 2;
    ushort_t* hbuf = (ushort_t*)(ws + p); p += (size_t)(RBMAX * BM) * F_DIM * 2;
    float*    ybuf = (float*)(ws + p);    p += (size_t)(RBMAX * BM) * D_DIM * 4;

    hipMemsetAsync(counts, 0, E_NUM * sizeof(int), stream);
    k_prep<<<P1_TOTAL, 256, 0, stream>>>(x, gw, counts, list, wsel, xb);
    k_finalize<<<1, 64, 0, stream>>>(counts, pcount, offs, nrb, rbmap);
    k_compact<<<dim3(T_TOKENS / 256, E_NUM), 256, 0, stream>>>(
        counts, pcount, offs, list, clist, rowOf);
    k_up_gemm<<<UP_BLOCKS, 256, 0, stream>>>(
        xb, wup, bup, nrb, rbmap, clist, hbuf);
    k_down_gemm<<<DN_BLOCKS, 256, 0, stream>>>(
        hbuf, wdn, bdn, nrb, rbmap, ybuf);
    k_combine<<<T_TOKENS / 4, 256, 0, stream>>>(ybuf, rowOf, wsel, out);
}

// Round 7
// 308.200 us; speedup vs baseline: 1.3704x; 1.3704x over previous
//
#include <hip/hip_runtime.h>
#include <hip/hip_bf16.h>
#include <math.h>

// Problem constants (B=2,S=2048 -> T=4096 tokens)
#define T_TOKENS 4096
#define D_DIM 768
#define F_DIM 3072
#define E_NUM 8

#define BM 128
#define BN 128
#define BK 32
#define RBMAX 72                 // max padded 128-row blocks
#define NBU (F_DIM / BN)         // 24
#define NBD (D_DIM / BN)         // 6
#define UP_BLOCKS (NBU * RBMAX)  // 1728
#define DBM 64                   // down-GEMM row-tile
#define DN_BLOCKS (NBD * RBMAX * 2)  // 864

typedef __attribute__((ext_vector_type(8))) short short8;
typedef __attribute__((ext_vector_type(4))) short short4v;
typedef __attribute__((ext_vector_type(4))) float float4v;
typedef unsigned short ushort_t;

__device__ __forceinline__ ushort_t f2bf(float f) {
    union { float f; unsigned u; } v; v.f = f;
    unsigned r = v.u + 0x7fffu + ((v.u >> 16) & 1u);   // RNE
    return (ushort_t)(r >> 16);
}

__device__ __forceinline__ float gelu_fast(float v) {
    float u = v + 0.044715f * v * v * v;
    return v / (1.f + __expf(-1.5957691216f * u));
}

#define GLOAD_LDS16(gp, lp) __builtin_amdgcn_global_load_lds( \
    (const __attribute__((address_space(1))) void*)(gp),      \
    (__attribute__((address_space(3))) void*)(lp), 16, 0, 0)

// ============================================================ prep
// transpose tiles (pipelined, 4 tiles/block) + gate + x->bf16
#define TB_WUP 4608
#define TB_WDN 4608
#define TRB ((TB_WUP + TB_WDN) / 4)   // 2304 pipelined transpose blocks
#define PB_GATE 1024
#define PB_CVT 1024
#define P1_TOTAL (TRB + PB_GATE + PB_CVT)

__device__ __forceinline__ void tile_ptrs(int g, const float* wup, const float* wdn,
                                          ushort_t* wupT, ushort_t* wdnT,
                                          const float*& ip, ushort_t*& op,
                                          int& R, int& C, int& r0, int& c0) {
    const float* in; ushort_t* o;
    if (g < TB_WUP) { in = wup; o = wupT; R = D_DIM; C = F_DIM; }
    else            { g -= TB_WUP; in = wdn; o = wdnT; R = F_DIM; C = D_DIM; }
    int tpr = C / 64, tpc = R / 64;
    int e = g / (tpr * tpc);
    int rem = g % (tpr * tpc);
    r0 = (rem / tpr) * 64;
    c0 = (rem % tpr) * 64;
    ip = in + (size_t)e * R * C;
    op = o + (size_t)e * R * C;
}

__global__ void k_prep(const float* __restrict__ x, const float* __restrict__ gw,
                       const float* __restrict__ wup, const float* __restrict__ wdn,
                       int* __restrict__ counts, int* __restrict__ list,
                       float* __restrict__ wsel, ushort_t* __restrict__ xb,
                       ushort_t* __restrict__ wupT, ushort_t* __restrict__ wdnT) {
    __shared__ float tile[64][65];
    int bid = blockIdx.x;

    if (bid < TRB) {
        // 4-tile software-pipelined transpose: load(n+1) issued before phase2(n)
        int t = threadIdx.x;
        int tr = t >> 4;             // 0..15
        int tc4 = (t & 15) * 4;      // col chunk
        int g0 = bid * 4;

        const float* ip; ushort_t* op; int R, C, r0, c0;
        tile_ptrs(g0, wup, wdn, wupT, wdnT, ip, op, R, C, r0, c0);
        float4v cur0, cur1, cur2, cur3, nx0, nx1, nx2, nx3;
        cur0 = *(const float4v*)&ip[(size_t)(r0 + tr) * C + c0 + tc4];
        cur1 = *(const float4v*)&ip[(size_t)(r0 + tr + 16) * C + c0 + tc4];
        cur2 = *(const float4v*)&ip[(size_t)(r0 + tr + 32) * C + c0 + tc4];
        cur3 = *(const float4v*)&ip[(size_t)(r0 + tr + 48) * C + c0 + tc4];

#pragma unroll 4
        for (int n = 0; n < 4; ++n) {
            __syncthreads();                       // prior phase2 readers done
            *(float4v*)&tile[tr][tc4] = cur0;      // implicit vmcnt wait here
            *(float4v*)&tile[tr + 16][tc4] = cur1;
            *(float4v*)&tile[tr + 32][tc4] = cur2;
            *(float4v*)&tile[tr + 48][tc4] = cur3;
            const float* ip2 = ip; ushort_t* op2 = op;
            int R2 = R, C2 = C, r02 = r0, c02 = c0;
            if (n < 3) {
                tile_ptrs(g0 + n + 1, wup, wdn, wupT, wdnT, ip2, op2, R2, C2, r02, c02);
                nx0 = *(const float4v*)&ip2[(size_t)(r02 + tr) * C2 + c02 + tc4];
                nx1 = *(const float4v*)&ip2[(size_t)(r02 + tr + 16) * C2 + c02 + tc4];
                nx2 = *(const float4v*)&ip2[(size_t)(r02 + tr + 32) * C2 + c02 + tc4];
                nx3 = *(const float4v*)&ip2[(size_t)(r02 + tr + 48) * C2 + c02 + tc4];
            }
            __syncthreads();
#pragma unroll
            for (int i = 0; i < 4; ++i) {
                int rr = tr + i * 16;              // output row (= original col c0+rr)
                short4v sv = { (short)f2bf(tile[tc4 + 0][rr]),
                               (short)f2bf(tile[tc4 + 1][rr]),
                               (short)f2bf(tile[tc4 + 2][rr]),
                               (short)f2bf(tile[tc4 + 3][rr]) };
                *(short4v*)&op[(size_t)(c0 + rr) * R + r0 + tc4] = sv;
            }
            cur0 = nx0; cur1 = nx1; cur2 = nx2; cur3 = nx3;
            ip = ip2; op = op2; R = R2; C = C2; r0 = r02; c0 = c02;
        }
        return;
    }
    bid -= TRB;

    if (bid < PB_GATE) {
        int wave = threadIdx.x >> 6, lane = threadIdx.x & 63;
        int t = bid * 4 + wave;
        float acc[E_NUM];
#pragma unroll
        for (int e = 0; e < E_NUM; ++e) acc[e] = 0.f;
        const float* xr = x + (size_t)t * D_DIM;
        for (int d = lane; d < D_DIM; d += 64) {
            float xv = xr[d];
            const float* g = gw + d * E_NUM;
#pragma unroll
            for (int e = 0; e < E_NUM; ++e) acc[e] += xv * g[e];
        }
#pragma unroll
        for (int e = 0; e < E_NUM; ++e) {
#pragma unroll
            for (int s = 32; s >= 1; s >>= 1) acc[e] += __shfl_xor(acc[e], s);
        }
        if (lane == 0) {
            float mx = acc[0];
#pragma unroll
            for (int e = 1; e < E_NUM; ++e) mx = fmaxf(mx, acc[e]);
            float p[E_NUM], sum = 0.f;
#pragma unroll
            for (int e = 0; e < E_NUM; ++e) { p[e] = expf(acc[e] - mx); sum += p[e]; }
            float inv = 1.f / sum;
#pragma unroll
            for (int e = 0; e < E_NUM; ++e) p[e] *= inv;
            int e1 = 0;
#pragma unroll
            for (int e = 1; e < E_NUM; ++e) if (p[e] > p[e1]) e1 = e;
            int e2 = (e1 == 0) ? 1 : 0;
#pragma unroll
            for (int e = 0; e < E_NUM; ++e) if (e != e1 && p[e] > p[e2]) e2 = e;
            int s1 = atomicAdd(&counts[e1], 1);
            list[e1 * T_TOKENS + s1] = t * 2 + 0;      // token | slot bit
            int s2 = atomicAdd(&counts[e2], 1);
            list[e2 * T_TOKENS + s2] = t * 2 + 1;
            wsel[t * 2 + 0] = p[e1];
            wsel[t * 2 + 1] = p[e2];
        }
        return;
    }
    bid -= PB_GATE;

    {   // x -> bf16
        int n4 = T_TOKENS * D_DIM / 4;
        for (int j = bid * 256 + threadIdx.x; j < n4; j += PB_CVT * 256) {
            float4v v = ((const float4v*)x)[j];
            unsigned long long o =
                (unsigned long long)f2bf(v[0]) |
                ((unsigned long long)f2bf(v[1]) << 16) |
                ((unsigned long long)f2bf(v[2]) << 32) |
                ((unsigned long long)f2bf(v[3]) << 48);
            ((unsigned long long*)xb)[j] = o;
        }
    }
}

// ---------------------------------------------------------------- finalize
__global__ void k_finalize(const int* __restrict__ counts, int* __restrict__ pcount,
                           int* __restrict__ offs, int* __restrict__ nrb,
                           int* __restrict__ rbmap) {
    if (threadIdx.x == 0) {
        int acc = 0, rb = 0;
        for (int e = 0; e < E_NUM; ++e) {
            int pc = (counts[e] + BM - 1) / BM * BM;
            pcount[e] = pc;
            offs[e] = acc;
            for (int i = 0; i < pc / BM; ++i) rbmap[rb++] = e;
            acc += pc;
        }
        nrb[0] = rb;
    }
}

// ---------------------------------------------------------------- compact
__global__ void k_compact(const int* __restrict__ counts, const int* __restrict__ pcount,
                          const int* __restrict__ offs, const int* __restrict__ list,
                          int* __restrict__ clist, int* __restrict__ rowOf) {
    int e = blockIdx.y;
    int s = blockIdx.x * 256 + threadIdx.x;
    if (s >= pcount[e]) return;
    int g = offs[e] + s;
    if (s < counts[e]) {
        int v = list[e * T_TOKENS + s];
        clist[g] = v >> 1;
        rowOf[v] = g;                 // v = tok*2 + slot
    } else {
        clist[g] = 0;                 // padding row gathers token 0 (output unused)
    }
}

// ---------------------------------------------------------------- up GEMM
// flat grid, XCD-chunk swizzle, rb-inner
__global__ void k_up_gemm(const ushort_t* __restrict__ xb, const ushort_t* __restrict__ wupT,
                          const float* __restrict__ b_up, const int* __restrict__ nrb,
                          const int* __restrict__ rbmap, const int* __restrict__ clist,
                          ushort_t* __restrict__ h) {
    int wg = blockIdx.x;
    int lin = (wg & 7) * (UP_BLOCKS / 8) + (wg >> 3);
    int nb = lin / RBMAX;
    int rb = lin % RBMAX;
    if (rb >= nrb[0]) return;
    int e = rbmap[rb];
    __shared__ __align__(16) ushort_t As[2][BM][BK];
    __shared__ __align__(16) ushort_t Bs[2][BN][BK];
    int t = threadIdx.x, wave = t >> 6, lane = t & 63;
    int wm = wave >> 1, wn = wave & 1;

    int row0 = rb * BM;
    int tokA0 = clist[row0 + (t >> 2)];
    int tokA1 = clist[row0 + 64 + (t >> 2)];
    const ushort_t* wb = wupT + (size_t)e * F_DIM * D_DIM + (size_t)(nb * BN) * D_DIM;

    float4v acc[4][4];
#pragma unroll
    for (int i = 0; i < 4; ++i)
#pragma unroll
        for (int j = 0; j < 4; ++j)
#pragma unroll
            for (int q = 0; q < 4; ++q) acc[i][j][q] = 0.f;

    int csw = (((t & 3) ^ ((t >> 3) & 3))) * 8;    // staged src chunk (swizzled)
    int swoff = (((lane >> 4) ^ (((lane & 15) >> 1) & 3))) * 8;  // read-side

    const ushort_t* gA0 = xb + (size_t)tokA0 * D_DIM + csw;
    const ushort_t* gA1 = xb + (size_t)tokA1 * D_DIM + csw;
    const ushort_t* gB0 = wb + (size_t)(t >> 2) * D_DIM + csw;
    const ushort_t* gB1 = wb + (size_t)(64 + (t >> 2)) * D_DIM + csw;

#define STAGE_UP(buf, kt) do { int k0 = (kt) * BK;                            \
        char* AsB = (char*)&As[buf][0][0]; char* BsB = (char*)&Bs[buf][0][0]; \
        GLOAD_LDS16(gA0 + k0, AsB + wave * 1024);                             \
        GLOAD_LDS16(gA1 + k0, AsB + 4096 + wave * 1024);                      \
        GLOAD_LDS16(gB0 + k0, BsB + wave * 1024);                             \
        GLOAD_LDS16(gB1 + k0, BsB + 4096 + wave * 1024); } while (0)

    STAGE_UP(0, 0);
    __syncthreads();
    const int nt = D_DIM / BK;
    for (int kt = 0; kt < nt; ++kt) {
        int buf = kt & 1;
        if (kt + 1 < nt) STAGE_UP(buf ^ 1, kt + 1);
        short8 af[4], bfr[4];
#pragma unroll
        for (int m = 0; m < 4; ++m)
            af[m] = *(const short8*)&As[buf][wm * 64 + m * 16 + (lane & 15)][swoff];
#pragma unroll
        for (int n = 0; n < 4; ++n)
            bfr[n] = *(const short8*)&Bs[buf][wn * 64 + n * 16 + (lane & 15)][swoff];
#pragma unroll
        for (int m = 0; m < 4; ++m)
#pragma unroll
            for (int n = 0; n < 4; ++n)
                acc[m][n] = __builtin_amdgcn_mfma_f32_16x16x32_bf16(af[m], bfr[n], acc[m][n], 0, 0, 0);
        __syncthreads();
    }

#pragma unroll
    for (int m = 0; m < 4; ++m) {
        int row_local = wm * 64 + m * 16 + (lane >> 4) * 4;
#pragma unroll
        for (int n = 0; n < 4; ++n) {
            int col = nb * BN + wn * 64 + n * 16 + (lane & 15);
            float bia = b_up[e * F_DIM + col];
#pragma unroll
            for (int j = 0; j < 4; ++j) {
                float v = acc[m][n][j] + bia;
                h[(size_t)(row0 + row_local + j) * F_DIM + col] = f2bf(gelu_fast(v));
            }
        }
    }
}

// ---------------------------------------------------------------- down GEMM
// 64x128 tile, plain fp32 stores into ybuf (bias folded), no atomics
__global__ void k_down_gemm(const ushort_t* __restrict__ h, const ushort_t* __restrict__ wdT,
                            const float* __restrict__ b_down, const int* __restrict__ nrb,
                            const int* __restrict__ rbmap, float* __restrict__ yb) {
    int wg = blockIdx.x;
    int lin = (wg & 7) * (DN_BLOCKS / 8) + (wg >> 3);
    int nb = lin / (RBMAX * 2);
    int rbD = lin % (RBMAX * 2);
    if ((rbD >> 1) >= nrb[0]) return;
    int e = rbmap[rbD >> 1];
    __shared__ __align__(16) ushort_t As[2][DBM][BK];
    __shared__ __align__(16) ushort_t Bs[2][BN][BK];
    int t = threadIdx.x, wave = t >> 6, lane = t & 63;
    int wm = wave >> 1, wn = wave & 1;

    int row0 = rbD * DBM;
    const ushort_t* ha = h + (size_t)row0 * F_DIM;
    const ushort_t* wb = wdT + (size_t)e * D_DIM * F_DIM + (size_t)(nb * BN) * F_DIM;

    float4v acc[2][4];
#pragma unroll
    for (int i = 0; i < 2; ++i)
#pragma unroll
        for (int j = 0; j < 4; ++j)
#pragma unroll
            for (int q = 0; q < 4; ++q) acc[i][j][q] = 0.f;

    int csw = (((t & 3) ^ ((t >> 3) & 3))) * 8;
    int swoff = (((lane >> 4) ^ (((lane & 15) >> 1) & 3))) * 8;

    const ushort_t* gA0 = ha + (size_t)(t >> 2) * F_DIM + csw;
    const ushort_t* gB0 = wb + (size_t)(t >> 2) * F_DIM + csw;
    const ushort_t* gB1 = wb + (size_t)(64 + (t >> 2)) * F_DIM + csw;

#define STAGE_DN(buf, kt) do { int k0 = (kt) * BK;                            \
        char* AsB = (char*)&As[buf][0][0]; char* BsB = (char*)&Bs[buf][0][0]; \
        GLOAD_LDS16(gA0 + k0, AsB + wave * 1024);                             \
        GLOAD_LDS16(gB0 + k0, BsB + wave * 1024);                             \
        GLOAD_LDS16(gB1 + k0, BsB + 4096 + wave * 1024); } while (0)

    STAGE_DN(0, 0);
    __syncthreads();
    const int nt = F_DIM / BK;
    for (int kt = 0; kt < nt; ++kt) {
        int buf = kt & 1;
        if (kt + 1 < nt) STAGE_DN(buf ^ 1, kt + 1);
        short8 af[2], bfr[4];
#pragma unroll
        for (int m = 0; m < 2; ++m)
            af[m] = *(const short8*)&As[buf][wm * 32 + m * 16 + (lane & 15)][swoff];
#pragma unroll
        for (int n = 0; n < 4; ++n)
            bfr[n] = *(const short8*)&Bs[buf][wn * 64 + n * 16 + (lane & 15)][swoff];
#pragma unroll
        for (int m = 0; m < 2; ++m)
#pragma unroll
            for (int n = 0; n < 4; ++n)
                acc[m][n] = __builtin_amdgcn_mfma_f32_16x16x32_bf16(af[m], bfr[n], acc[m][n], 0, 0, 0);
        __syncthreads();
    }

#pragma unroll
    for (int m = 0; m < 2; ++m) {
        int row_local = wm * 32 + m * 16 + (lane >> 4) * 4;
#pragma unroll
        for (int n = 0; n < 4; ++n) {
            int col = nb * BN + wn * 64 + n * 16 + (lane & 15);
            float bia = b_down[e * D_DIM + col];
#pragma unroll
            for (int j = 0; j < 4; ++j) {
                yb[(size_t)(row0 + row_local + j) * D_DIM + col] = acc[m][n][j] + bia;
            }
        }
    }
}

// ---------------------------------------------------------------- combine
__global__ void k_combine(const float* __restrict__ yb, const int* __restrict__ rowOf,
                          const float* __restrict__ wsel, float* __restrict__ out) {
    int wave = threadIdx.x >> 6, lane = threadIdx.x & 63;
    int t = blockIdx.x * 4 + wave;
    int g0 = rowOf[t * 2], g1 = rowOf[t * 2 + 1];
    float w0 = wsel[t * 2], w1 = wsel[t * 2 + 1];
    const float4v* y0 = (const float4v*)(yb + (size_t)g0 * D_DIM);
    const float4v* y1 = (const float4v*)(yb + (size_t)g1 * D_DIM);
    float4v* o = (float4v*)(out + (size_t)t * D_DIM);
#pragma unroll
    for (int i = 0; i < 3; ++i) {
        int idx = lane + i * 64;
        float4v a = y0[idx], b = y1[idx];
        float4v r;
#pragma unroll
        for (int q = 0; q < 4; ++q) r[q] = w0 * a[q] + w1 * b[q];
        o[idx] = r;
    }
}

// ---------------------------------------------------------------- launch
extern "C" void kernel_launch(void* const* d_in, const int* in_sizes, int n_in,
                              void* d_out, int out_size, void* d_ws, size_t ws_size,
                              hipStream_t stream) {
    const float* x   = (const float*)d_in[0];   // [2,2048,768]
    const float* gw  = (const float*)d_in[1];   // [768,8]
    const float* wup = (const float*)d_in[2];   // [8,768,3072]
    const float* bup = (const float*)d_in[3];   // [8,3072]
    const float* wdn = (const float*)d_in[4];   // [8,3072,768]
    const float* bdn = (const float*)d_in[5];   // [8,768]
    float* out = (float*)d_out;

    char* ws = (char*)d_ws;
    int*   counts = (int*)(ws);
    int*   pcount = (int*)(ws + 32);
    int*   offs   = (int*)(ws + 64);
    int*   nrb    = (int*)(ws + 96);
    int*   rbmap  = (int*)(ws + 128);
    int*   list   = (int*)(ws + 1024);
    size_t p = 1024 + (size_t)E_NUM * T_TOKENS * 4;
    int*   clist  = (int*)(ws + p); p += (size_t)(RBMAX * BM) * 4;
    int*   rowOf  = (int*)(ws + p); p += (size_t)T_TOKENS * 2 * 4;
    float* wsel   = (float*)(ws + p); p += (size_t)T_TOKENS * 2 * 4;
    p = (p + 255) & ~(size_t)255;
    size_t p_xb = p;
    ushort_t* xb   = (ushort_t*)(ws + p); p += (size_t)T_TOKENS * D_DIM * 2;
    ushort_t* wupT = (ushort_t*)(ws + p); p += (size_t)E_NUM * D_DIM * F_DIM * 2;
    ushort_t* wdnT = (ushort_t*)(ws + p); p += (size_t)E_NUM * D_DIM * F_DIM * 2;
    ushort_t* hbuf = (ushort_t*)(ws + p); p += (size_t)(RBMAX * BM) * F_DIM * 2;
    // ybuf aliases xb+wupT (both dead once down GEMM runs): 28.3MB <= 43.5MB
    float* ybuf = (float*)(ws + p_xb);

    hipMemsetAsync(counts, 0, E_NUM * sizeof(int), stream);
    k_prep<<<P1_TOTAL, 256, 0, stream>>>(x, gw, wup, wdn, counts, list, wsel,
                                         xb, wupT, wdnT);
    k_finalize<<<1, 64, 0, stream>>>(counts, pcount, offs, nrb, rbmap);
    k_compact<<<dim3(T_TOKENS / 256, E_NUM), 256, 0, stream>>>(
        counts, pcount, offs, list, clist, rowOf);
    k_up_gemm<<<UP_BLOCKS, 256, 0, stream>>>(
        xb, wupT, bup, nrb, rbmap, clist, hbuf);
    k_down_gemm<<<DN_BLOCKS, 256, 0, stream>>>(
        hbuf, wdn == nullptr ? nullptr : wdnT, bdn, nrb, rbmap, ybuf);
    k_combine<<<T_TOKENS / 4, 256, 0, stream>>>(ybuf, rowOf, wsel, out);
}

// Round 8
// 308.000 us; speedup vs baseline: 1.3713x; 1.0007x over previous
//
#include <hip/hip_runtime.h>
#include <hip/hip_bf16.h>
#include <math.h>

// Problem constants (B=2,S=2048 -> T=4096 tokens)
#define T_TOKENS 4096
#define D_DIM 768
#define F_DIM 3072
#define E_NUM 8

#define BM 128
#define BN 128
#define BK 32
#define RBMAX 72                 // max padded 128-row blocks
#define NBU (F_DIM / BN)         // 24
#define NBD (D_DIM / BN)         // 6
#define UP_BLOCKS (NBU * RBMAX)  // 1728
#define DBM 64                   // down-GEMM row-tile
#define DN_BLOCKS (NBD * RBMAX * 2)  // 864

// 64x64 tiles per weight tensor: 8*12*48 = 4608. Per block: 4 waves x 2 tiles.
#define TRB 576                  // 4608 / 8
#define TILE_LDS (64 * 66)       // bf16 elems per wave-private tile

typedef __attribute__((ext_vector_type(8))) short short8;
typedef __attribute__((ext_vector_type(4))) short short4v;
typedef __attribute__((ext_vector_type(4))) float float4v;
typedef unsigned short ushort_t;

__device__ __forceinline__ ushort_t f2bf(float f) {
    union { float f; unsigned u; } v; v.f = f;
    unsigned r = v.u + 0x7fffu + ((v.u >> 16) & 1u);   // RNE
    return (ushort_t)(r >> 16);
}

__device__ __forceinline__ float gelu_fast(float v) {
    float u = v + 0.044715f * v * v * v;
    return v / (1.f + __expf(-1.5957691216f * u));
}

#define GLOAD_LDS16(gp, lp) __builtin_amdgcn_global_load_lds( \
    (const __attribute__((address_space(1))) void*)(gp),      \
    (__attribute__((address_space(3))) void*)(lp), 16, 0, 0)

// ---------------------------------------------------------------- tile coords
__device__ __forceinline__ void tile_coords(int g, int R, int C,
                                            int& e, int& r0, int& c0) {
    int tpr = C / 64, tpc = R / 64;
    e = g / (tpr * tpc);
    int rem = g % (tpr * tpc);
    r0 = (rem / tpr) * 64;
    c0 = (rem % tpr) * 64;
}

// ------------------------------------------------- per-WAVE barrier-free transpose
// one 64x64 tile: in [R][C] fp32 -> out [C][R] bf16. No __syncthreads:
// wave-private LDS slice, within-wave lgkmcnt fence only.
__device__ __forceinline__ void wave_transpose64(const float* __restrict__ ip,
                                                 ushort_t* __restrict__ op,
                                                 int R, int C, int r0, int c0,
                                                 ushort_t* __restrict__ tl) {
    int l = threadIdx.x & 63;
    int lr = l >> 4;             // 0..3
    int lc4 = (l & 15) * 4;      // 0,4,...,60

    // phase 1: 16 independent coalesced float4 loads (4KB in flight)
    float4v v[16];
#pragma unroll
    for (int i = 0; i < 16; ++i)
        v[i] = *(const float4v*)&ip[(size_t)(r0 + 4 * i + lr) * C + c0 + lc4];
    // cvt + LDS write (compiler staggers vmcnt waits per use)
#pragma unroll
    for (int i = 0; i < 16; ++i) {
        short4v s = { (short)f2bf(v[i][0]), (short)f2bf(v[i][1]),
                      (short)f2bf(v[i][2]), (short)f2bf(v[i][3]) };
        *(short4v*)&tl[(4 * i + lr) * 66 + lc4] = s;
    }
    // within-wave fence: all LDS writes visible to this wave's reads
    asm volatile("s_waitcnt lgkmcnt(0)" ::: "memory");

    // phase 2: column reads -> 128B-segment coalesced bf16 stores
#pragma unroll
    for (int i = 0; i < 16; ++i) {
        int rr = 4 * i + lr;                     // output row (= orig col c0+rr)
        short4v s = { (short)tl[(lc4 + 0) * 66 + rr],
                      (short)tl[(lc4 + 1) * 66 + rr],
                      (short)tl[(lc4 + 2) * 66 + rr],
                      (short)tl[(lc4 + 3) * 66 + rr] };
        *(short4v*)&op[(size_t)(c0 + rr) * R + r0 + lc4] = s;
    }
}

// ============================================================ prep
// [0,576): wup transpose (per-wave) | [576,1600): gate | [1600,2112): x->bf16
#define PB_GATE 1024
#define PB_CVT 512
#define P1_TOTAL (TRB + PB_GATE + PB_CVT)

__global__ void k_prep(const float* __restrict__ x, const float* __restrict__ gw,
                       const float* __restrict__ wup,
                       int* __restrict__ counts, int* __restrict__ list,
                       float* __restrict__ wsel, ushort_t* __restrict__ xb,
                       ushort_t* __restrict__ wupT) {
    __shared__ ushort_t ttile[4][TILE_LDS];
    int bid = blockIdx.x;

    if (bid < TRB) {
        int wave = threadIdx.x >> 6;
        ushort_t* tl = &ttile[wave][0];
#pragma unroll 2
        for (int it = 0; it < 2; ++it) {
            int g = (bid * 4 + wave) * 2 + it;   // 0..4607
            int e, r0, c0;
            tile_coords(g, D_DIM, F_DIM, e, r0, c0);
            const float* ip = wup + (size_t)e * D_DIM * F_DIM;
            ushort_t* op = wupT + (size_t)e * D_DIM * F_DIM;
            wave_transpose64(ip, op, D_DIM, F_DIM, r0, c0, tl);
        }
        return;
    }
    bid -= TRB;

    if (bid < PB_GATE) {
        int wave = threadIdx.x >> 6, lane = threadIdx.x & 63;
        int t = bid * 4 + wave;
        float acc[E_NUM];
#pragma unroll
        for (int e = 0; e < E_NUM; ++e) acc[e] = 0.f;
        const float* xr = x + (size_t)t * D_DIM;
        for (int d = lane; d < D_DIM; d += 64) {
            float xv = xr[d];
            const float* g = gw + d * E_NUM;
#pragma unroll
            for (int e = 0; e < E_NUM; ++e) acc[e] += xv * g[e];
        }
#pragma unroll
        for (int e = 0; e < E_NUM; ++e) {
#pragma unroll
            for (int s = 32; s >= 1; s >>= 1) acc[e] += __shfl_xor(acc[e], s);
        }
        if (lane == 0) {
            float mx = acc[0];
#pragma unroll
            for (int e = 1; e < E_NUM; ++e) mx = fmaxf(mx, acc[e]);
            float p[E_NUM], sum = 0.f;
#pragma unroll
            for (int e = 0; e < E_NUM; ++e) { p[e] = expf(acc[e] - mx); sum += p[e]; }
            float inv = 1.f / sum;
#pragma unroll
            for (int e = 0; e < E_NUM; ++e) p[e] *= inv;
            int e1 = 0;
#pragma unroll
            for (int e = 1; e < E_NUM; ++e) if (p[e] > p[e1]) e1 = e;
            int e2 = (e1 == 0) ? 1 : 0;
#pragma unroll
            for (int e = 0; e < E_NUM; ++e) if (e != e1 && p[e] > p[e2]) e2 = e;
            int s1 = atomicAdd(&counts[e1], 1);
            list[e1 * T_TOKENS + s1] = t * 2 + 0;      // token | slot bit
            int s2 = atomicAdd(&counts[e2], 1);
            list[e2 * T_TOKENS + s2] = t * 2 + 1;
            wsel[t * 2 + 0] = p[e1];
            wsel[t * 2 + 1] = p[e2];
        }
        return;
    }
    bid -= PB_GATE;

    {   // x -> bf16
        int n4 = T_TOKENS * D_DIM / 4;
        for (int j = bid * 256 + threadIdx.x; j < n4; j += PB_CVT * 256) {
            float4v v = ((const float4v*)x)[j];
            unsigned long long o =
                (unsigned long long)f2bf(v[0]) |
                ((unsigned long long)f2bf(v[1]) << 16) |
                ((unsigned long long)f2bf(v[2]) << 32) |
                ((unsigned long long)f2bf(v[3]) << 48);
            ((unsigned long long*)xb)[j] = o;
        }
    }
}

// ---------------------------------------------------------------- finalize
__global__ void k_finalize(const int* __restrict__ counts, int* __restrict__ pcount,
                           int* __restrict__ offs, int* __restrict__ nrb,
                           int* __restrict__ rbmap) {
    if (threadIdx.x == 0) {
        int acc = 0, rb = 0;
        for (int e = 0; e < E_NUM; ++e) {
            int pc = (counts[e] + BM - 1) / BM * BM;
            pcount[e] = pc;
            offs[e] = acc;
            for (int i = 0; i < pc / BM; ++i) rbmap[rb++] = e;
            acc += pc;
        }
        nrb[0] = rb;
    }
}

// ---------------------------------------------------------------- compact
__global__ void k_compact(const int* __restrict__ counts, const int* __restrict__ pcount,
                          const int* __restrict__ offs, const int* __restrict__ list,
                          int* __restrict__ clist, int* __restrict__ rowOf) {
    int e = blockIdx.y;
    int s = blockIdx.x * 256 + threadIdx.x;
    if (s >= pcount[e]) return;
    int g = offs[e] + s;
    if (s < counts[e]) {
        int v = list[e * T_TOKENS + s];
        clist[g] = v >> 1;
        rowOf[v] = g;                 // v = tok*2 + slot
    } else {
        clist[g] = 0;                 // padding row gathers token 0 (output unused)
    }
}

// ------------------------------------------- up GEMM + wdn transpose (fused)
// blocks [0,1728): up GEMM | [1728,2304): wdn transpose rides the memory pipe
__global__ void k_up_gemm(const ushort_t* __restrict__ xb, const ushort_t* __restrict__ wupT,
                          const float* __restrict__ b_up, const int* __restrict__ nrb,
                          const int* __restrict__ rbmap, const int* __restrict__ clist,
                          ushort_t* __restrict__ h,
                          const float* __restrict__ wdn, ushort_t* __restrict__ wdnT) {
    __shared__ __align__(16) char smem[4 * TILE_LDS * 2];   // 33792B

    if (blockIdx.x >= UP_BLOCKS) {
        int bid2 = blockIdx.x - UP_BLOCKS;                   // 0..575
        int wave = threadIdx.x >> 6;
        ushort_t* tl = (ushort_t*)(smem) + wave * TILE_LDS;
#pragma unroll 2
        for (int it = 0; it < 2; ++it) {
            int g = (bid2 * 4 + wave) * 2 + it;              // 0..4607
            int e, r0, c0;
            tile_coords(g, F_DIM, D_DIM, e, r0, c0);
            const float* ip = wdn + (size_t)e * F_DIM * D_DIM;
            ushort_t* op = wdnT + (size_t)e * F_DIM * D_DIM;
            wave_transpose64(ip, op, F_DIM, D_DIM, r0, c0, tl);
        }
        return;
    }

    int wg = blockIdx.x;
    int lin = (wg & 7) * (UP_BLOCKS / 8) + (wg >> 3);
    int nb = lin / RBMAX;
    int rb = lin % RBMAX;
    if (rb >= nrb[0]) return;
    int e = rbmap[rb];
    ushort_t (*As)[BM][BK] = reinterpret_cast<ushort_t(*)[BM][BK]>(smem);
    ushort_t (*Bs)[BM][BK] = reinterpret_cast<ushort_t(*)[BM][BK]>(smem + 16384);
    int t = threadIdx.x, wave = t >> 6, lane = t & 63;
    int wm = wave >> 1, wn = wave & 1;

    int row0 = rb * BM;
    int tokA0 = clist[row0 + (t >> 2)];
    int tokA1 = clist[row0 + 64 + (t >> 2)];
    const ushort_t* wb = wupT + (size_t)e * F_DIM * D_DIM + (size_t)(nb * BN) * D_DIM;

    float4v acc[4][4];
#pragma unroll
    for (int i = 0; i < 4; ++i)
#pragma unroll
        for (int j = 0; j < 4; ++j)
#pragma unroll
            for (int q = 0; q < 4; ++q) acc[i][j][q] = 0.f;

    int csw = (((t & 3) ^ ((t >> 3) & 3))) * 8;    // staged src chunk (swizzled)
    int swoff = (((lane >> 4) ^ (((lane & 15) >> 1) & 3))) * 8;  // read-side

    const ushort_t* gA0 = xb + (size_t)tokA0 * D_DIM + csw;
    const ushort_t* gA1 = xb + (size_t)tokA1 * D_DIM + csw;
    const ushort_t* gB0 = wb + (size_t)(t >> 2) * D_DIM + csw;
    const ushort_t* gB1 = wb + (size_t)(64 + (t >> 2)) * D_DIM + csw;

#define STAGE_UP(buf, kt) do { int k0 = (kt) * BK;                            \
        char* AsB = (char*)&As[buf][0][0]; char* BsB = (char*)&Bs[buf][0][0]; \
        GLOAD_LDS16(gA0 + k0, AsB + wave * 1024);                             \
        GLOAD_LDS16(gA1 + k0, AsB + 4096 + wave * 1024);                      \
        GLOAD_LDS16(gB0 + k0, BsB + wave * 1024);                             \
        GLOAD_LDS16(gB1 + k0, BsB + 4096 + wave * 1024); } while (0)

    STAGE_UP(0, 0);
    __syncthreads();
    const int nt = D_DIM / BK;
    for (int kt = 0; kt < nt; ++kt) {
        int buf = kt & 1;
        if (kt + 1 < nt) STAGE_UP(buf ^ 1, kt + 1);
        short8 af[4], bfr[4];
#pragma unroll
        for (int m = 0; m < 4; ++m)
            af[m] = *(const short8*)&As[buf][wm * 64 + m * 16 + (lane & 15)][swoff];
#pragma unroll
        for (int n = 0; n < 4; ++n)
            bfr[n] = *(const short8*)&Bs[buf][wn * 64 + n * 16 + (lane & 15)][swoff];
#pragma unroll
        for (int m = 0; m < 4; ++m)
#pragma unroll
            for (int n = 0; n < 4; ++n)
                acc[m][n] = __builtin_amdgcn_mfma_f32_16x16x32_bf16(af[m], bfr[n], acc[m][n], 0, 0, 0);
        __syncthreads();
    }

#pragma unroll
    for (int m = 0; m < 4; ++m) {
        int row_local = wm * 64 + m * 16 + (lane >> 4) * 4;
#pragma unroll
        for (int n = 0; n < 4; ++n) {
            int col = nb * BN + wn * 64 + n * 16 + (lane & 15);
            float bia = b_up[e * F_DIM + col];
#pragma unroll
            for (int j = 0; j < 4; ++j) {
                float v = acc[m][n][j] + bia;
                h[(size_t)(row0 + row_local + j) * F_DIM + col] = f2bf(gelu_fast(v));
            }
        }
    }
}

// ---------------------------------------------------------------- down GEMM
// 64x128 tile, plain fp32 stores into ybuf (bias folded), no atomics
__global__ void k_down_gemm(const ushort_t* __restrict__ h, const ushort_t* __restrict__ wdT,
                            const float* __restrict__ b_down, const int* __restrict__ nrb,
                            const int* __restrict__ rbmap, float* __restrict__ yb) {
    int wg = blockIdx.x;
    int lin = (wg & 7) * (DN_BLOCKS / 8) + (wg >> 3);
    int nb = lin / (RBMAX * 2);
    int rbD = lin % (RBMAX * 2);
    if ((rbD >> 1) >= nrb[0]) return;
    int e = rbmap[rbD >> 1];
    __shared__ __align__(16) ushort_t As[2][DBM][BK];
    __shared__ __align__(16) ushort_t Bs[2][BN][BK];
    int t = threadIdx.x, wave = t >> 6, lane = t & 63;
    int wm = wave >> 1, wn = wave & 1;

    int row0 = rbD * DBM;
    const ushort_t* ha = h + (size_t)row0 * F_DIM;
    const ushort_t* wb = wdT + (size_t)e * D_DIM * F_DIM + (size_t)(nb * BN) * F_DIM;

    float4v acc[2][4];
#pragma unroll
    for (int i = 0; i < 2; ++i)
#pragma unroll
        for (int j = 0; j < 4; ++j)
#pragma unroll
            for (int q = 0; q < 4; ++q) acc[i][j][q] = 0.f;

    int csw = (((t & 3) ^ ((t >> 3) & 3))) * 8;
    int swoff = (((lane >> 4) ^ (((lane & 15) >> 1) & 3))) * 8;

    const ushort_t* gA0 = ha + (size_t)(t >> 2) * F_DIM + csw;
    const ushort_t* gB0 = wb + (size_t)(t >> 2) * F_DIM + csw;
    const ushort_t* gB1 = wb + (size_t)(64 + (t >> 2)) * F_DIM + csw;

#define STAGE_DN(buf, kt) do { int k0 = (kt) * BK;                            \
        char* AsB = (char*)&As[buf][0][0]; char* BsB = (char*)&Bs[buf][0][0]; \
        GLOAD_LDS16(gA0 + k0, AsB + wave * 1024);                             \
        GLOAD_LDS16(gB0 + k0, BsB + wave * 1024);                             \
        GLOAD_LDS16(gB1 + k0, BsB + 4096 + wave * 1024); } while (0)

    STAGE_DN(0, 0);
    __syncthreads();
    const int nt = F_DIM / BK;
    for (int kt = 0; kt < nt; ++kt) {
        int buf = kt & 1;
        if (kt + 1 < nt) STAGE_DN(buf ^ 1, kt + 1);
        short8 af[2], bfr[4];
#pragma unroll
        for (int m = 0; m < 2; ++m)
            af[m] = *(const short8*)&As[buf][wm * 32 + m * 16 + (lane & 15)][swoff];
#pragma unroll
        for (int n = 0; n < 4; ++n)
            bfr[n] = *(const short8*)&Bs[buf][wn * 64 + n * 16 + (lane & 15)][swoff];
#pragma unroll
        for (int m = 0; m < 2; ++m)
#pragma unroll
            for (int n = 0; n < 4; ++n)
                acc[m][n] = __builtin_amdgcn_mfma_f32_16x16x32_bf16(af[m], bfr[n], acc[m][n], 0, 0, 0);
        __syncthreads();
    }

#pragma unroll
    for (int m = 0; m < 2; ++m) {
        int row_local = wm * 32 + m * 16 + (lane >> 4) * 4;
#pragma unroll
        for (int n = 0; n < 4; ++n) {
            int col = nb * BN + wn * 64 + n * 16 + (lane & 15);
            float bia = b_down[e * D_DIM + col];
#pragma unroll
            for (int j = 0; j < 4; ++j) {
                yb[(size_t)(row0 + row_local + j) * D_DIM + col] = acc[m][n][j] + bia;
            }
        }
    }
}

// ---------------------------------------------------------------- combine
__global__ void k_combine(const float* __restrict__ yb, const int* __restrict__ rowOf,
                          const float* __restrict__ wsel, float* __restrict__ out) {
    int wave = threadIdx.x >> 6, lane = threadIdx.x & 63;
    int t = blockIdx.x * 4 + wave;
    int g0 = rowOf[t * 2], g1 = rowOf[t * 2 + 1];
    float w0 = wsel[t * 2], w1 = wsel[t * 2 + 1];
    const float4v* y0 = (const float4v*)(yb + (size_t)g0 * D_DIM);
    const float4v* y1 = (const float4v*)(yb + (size_t)g1 * D_DIM);
    float4v* o = (float4v*)(out + (size_t)t * D_DIM);
#pragma unroll
    for (int i = 0; i < 3; ++i) {
        int idx = lane + i * 64;
        float4v a = y0[idx], b = y1[idx];
        float4v r;
#pragma unroll
        for (int q = 0; q < 4; ++q) r[q] = w0 * a[q] + w1 * b[q];
        o[idx] = r;
    }
}

// ---------------------------------------------------------------- launch
extern "C" void kernel_launch(void* const* d_in, const int* in_sizes, int n_in,
                              void* d_out, int out_size, void* d_ws, size_t ws_size,
                              hipStream_t stream) {
    const float* x   = (const float*)d_in[0];   // [2,2048,768]
    const float* gw  = (const float*)d_in[1];   // [768,8]
    const float* wup = (const float*)d_in[2];   // [8,768,3072]
    const float* bup = (const float*)d_in[3];   // [8,3072]
    const float* wdn = (const float*)d_in[4];   // [8,3072,768]
    const float* bdn = (const float*)d_in[5];   // [8,768]
    float* out = (float*)d_out;

    char* ws = (char*)d_ws;
    int*   counts = (int*)(ws);
    int*   pcount = (int*)(ws + 32);
    int*   offs   = (int*)(ws + 64);
    int*   nrb    = (int*)(ws + 96);
    int*   rbmap  = (int*)(ws + 128);
    int*   list   = (int*)(ws + 1024);
    size_t p = 1024 + (size_t)E_NUM * T_TOKENS * 4;
    int*   clist  = (int*)(ws + p); p += (size_t)(RBMAX * BM) * 4;
    int*   rowOf  = (int*)(ws + p); p += (size_t)T_TOKENS * 2 * 4;
    float* wsel   = (float*)(ws + p); p += (size_t)T_TOKENS * 2 * 4;
    p = (p + 255) & ~(size_t)255;
    size_t p_xb = p;
    ushort_t* xb   = (ushort_t*)(ws + p); p += (size_t)T_TOKENS * D_DIM * 2;
    ushort_t* wupT = (ushort_t*)(ws + p); p += (size_t)E_NUM * D_DIM * F_DIM * 2;
    ushort_t* wdnT = (ushort_t*)(ws + p); p += (size_t)E_NUM * D_DIM * F_DIM * 2;
    ushort_t* hbuf = (ushort_t*)(ws + p); p += (size_t)(RBMAX * BM) * F_DIM * 2;
    // ybuf aliases xb+wupT (both dead once down GEMM runs): 28.3MB <= 43.5MB
    float* ybuf = (float*)(ws + p_xb);

    hipMemsetAsync(counts, 0, E_NUM * sizeof(int), stream);
    k_prep<<<P1_TOTAL, 256, 0, stream>>>(x, gw, wup, counts, list, wsel, xb, wupT);
    k_finalize<<<1, 64, 0, stream>>>(counts, pcount, offs, nrb, rbmap);
    k_compact<<<dim3(T_TOKENS / 256, E_NUM), 256, 0, stream>>>(
        counts, pcount, offs, list, clist, rowOf);
    k_up_gemm<<<UP_BLOCKS + TRB, 256, 0, stream>>>(
        xb, wupT, bup, nrb, rbmap, clist, hbuf, wdn, wdnT);
    k_down_gemm<<<DN_BLOCKS, 256, 0, stream>>>(
        hbuf, wdnT, bdn, nrb, rbmap, ybuf);
    k_combine<<<T_TOKENS / 4, 256, 0, stream>>>(ybuf, rowOf, wsel, out);
}

// Round 9
// 234.584 us; speedup vs baseline: 1.8004x; 1.3130x over previous
//
#include <hip/hip_runtime.h>
#include <hip/hip_bf16.h>
#include <math.h>

// Problem constants (B=2,S=2048 -> T=4096 tokens)
#define T_TOKENS 4096
#define D_DIM 768
#define F_DIM 3072
#define E_NUM 8

#define BM 128
#define BN 128
#define BK 32
#define RBMAX 72                 // max padded 128-row blocks
#define NBU (F_DIM / BN)         // 24
#define NBD (D_DIM / BN)         // 6
#define UP_BLOCKS (NBU * RBMAX)  // 1728
#define DBM 64                   // down-GEMM row-tile
#define DN_BLOCKS (NBD * RBMAX * 2)  // 864

#define TILE_LDS (64 * 66)       // bf16 elems per wave-private transpose tile
#define TRT_WUP 4608             // 64x64 tiles in wup
#define TRT_TOT 9216             // + wdn

typedef __attribute__((ext_vector_type(8))) short short8;
typedef __attribute__((ext_vector_type(4))) short short4v;
typedef __attribute__((ext_vector_type(4))) float float4v;
typedef unsigned short ushort_t;

__device__ __forceinline__ ushort_t f2bf(float f) {
    union { float f; unsigned u; } v; v.f = f;
    unsigned r = v.u + 0x7fffu + ((v.u >> 16) & 1u);   // RNE
    return (ushort_t)(r >> 16);
}

__device__ __forceinline__ float gelu_fast(float v) {
    float u = v + 0.044715f * v * v * v;
    return v / (1.f + __expf(-1.5957691216f * u));
}

#define GLOAD_LDS16(gp, lp) __builtin_amdgcn_global_load_lds( \
    (const __attribute__((address_space(1))) void*)(gp),      \
    (__attribute__((address_space(3))) void*)(lp), 16, 0, 0)

// ---------------------------------------------------------------- tile coords
__device__ __forceinline__ void tile_coords(int g, int R, int C,
                                            int& e, int& r0, int& c0) {
    int tpr = C / 64, tpc = R / 64;
    e = g / (tpr * tpc);
    int rem = g % (tpr * tpc);
    r0 = (rem / tpr) * 64;
    c0 = (rem % tpr) * 64;
}

// ------------------------------------------------- per-WAVE barrier-free transpose
__device__ __forceinline__ void wave_transpose64(const float* __restrict__ ip,
                                                 ushort_t* __restrict__ op,
                                                 int R, int C, int r0, int c0,
                                                 ushort_t* __restrict__ tl) {
    int l = threadIdx.x & 63;
    int lr = l >> 4;             // 0..3
    int lc4 = (l & 15) * 4;      // 0,4,...,60

    float4v v[16];
#pragma unroll
    for (int i = 0; i < 16; ++i)
        v[i] = *(const float4v*)&ip[(size_t)(r0 + 4 * i + lr) * C + c0 + lc4];
#pragma unroll
    for (int i = 0; i < 16; ++i) {
        short4v s = { (short)f2bf(v[i][0]), (short)f2bf(v[i][1]),
                      (short)f2bf(v[i][2]), (short)f2bf(v[i][3]) };
        *(short4v*)&tl[(4 * i + lr) * 66 + lc4] = s;
    }
    asm volatile("s_waitcnt lgkmcnt(0)" ::: "memory");
#pragma unroll
    for (int i = 0; i < 16; ++i) {
        int rr = 4 * i + lr;                     // output row (= orig col c0+rr)
        short4v s = { (short)tl[(lc4 + 0) * 66 + rr],
                      (short)tl[(lc4 + 1) * 66 + rr],
                      (short)tl[(lc4 + 2) * 66 + rr],
                      (short)tl[(lc4 + 3) * 66 + rr] };
        *(short4v*)&op[(size_t)(c0 + rr) * R + r0 + lc4] = s;
    }
}

// ---------------------------------------------------------------- transpose kernel
// both weight tensors, 1 tile per wave, 2304 blocks (4 blocks/CU at 33.8KB LDS)
__global__ __launch_bounds__(256) void k_trans(const float* __restrict__ wup,
                                               const float* __restrict__ wdn,
                                               ushort_t* __restrict__ wupT,
                                               ushort_t* __restrict__ wdnT) {
    __shared__ ushort_t ttile[4][TILE_LDS];
    int wave = threadIdx.x >> 6;
    int g = blockIdx.x * 4 + wave;               // 0..9215
    const float* in; ushort_t* outp; int R, C;
    if (g < TRT_WUP) { in = wup; outp = wupT; R = D_DIM; C = F_DIM; }
    else { g -= TRT_WUP; in = wdn; outp = wdnT; R = F_DIM; C = D_DIM; }
    int e, r0, c0;
    tile_coords(g, R, C, e, r0, c0);
    wave_transpose64(in + (size_t)e * R * C, outp + (size_t)e * R * C,
                     R, C, r0, c0, &ttile[wave][0]);
}

// ---------------------------------------------------------------- gate kernel
// 16 tokens/block (1024 thr), LDS histogram -> 8 global atomics per block
__global__ __launch_bounds__(1024) void k_gate(const float* __restrict__ x,
                                               const float* __restrict__ gw,
                                               int* __restrict__ counts,
                                               int* __restrict__ list,
                                               float* __restrict__ wsel) {
    __shared__ int hist[E_NUM];
    __shared__ int base[E_NUM];
    int wave = threadIdx.x >> 6, lane = threadIdx.x & 63;
    int t = blockIdx.x * 16 + wave;

    float acc[E_NUM];
#pragma unroll
    for (int e = 0; e < E_NUM; ++e) acc[e] = 0.f;
    const float* xr = x + (size_t)t * D_DIM;
    for (int d = lane; d < D_DIM; d += 64) {
        float xv = xr[d];
        const float* g = gw + d * E_NUM;
#pragma unroll
        for (int e = 0; e < E_NUM; ++e) acc[e] += xv * g[e];
    }
#pragma unroll
    for (int e = 0; e < E_NUM; ++e) {
#pragma unroll
        for (int s = 32; s >= 1; s >>= 1) acc[e] += __shfl_xor(acc[e], s);
    }

    if (threadIdx.x < E_NUM) hist[threadIdx.x] = 0;
    __syncthreads();

    int e1 = 0, e2 = 0, s1 = 0, s2 = 0;
    if (lane == 0) {
        float mx = acc[0];
#pragma unroll
        for (int e = 1; e < E_NUM; ++e) mx = fmaxf(mx, acc[e]);
        float p[E_NUM], sum = 0.f;
#pragma unroll
        for (int e = 0; e < E_NUM; ++e) { p[e] = expf(acc[e] - mx); sum += p[e]; }
        float inv = 1.f / sum;
#pragma unroll
        for (int e = 0; e < E_NUM; ++e) p[e] *= inv;
#pragma unroll
        for (int e = 1; e < E_NUM; ++e) if (p[e] > p[e1]) e1 = e;
        e2 = (e1 == 0) ? 1 : 0;
#pragma unroll
        for (int e = 0; e < E_NUM; ++e) if (e != e1 && p[e] > p[e2]) e2 = e;
        s1 = atomicAdd(&hist[e1], 1);            // LDS atomic
        s2 = atomicAdd(&hist[e2], 1);
        wsel[t * 2 + 0] = p[e1];
        wsel[t * 2 + 1] = p[e2];
    }
    __syncthreads();
    if (threadIdx.x < E_NUM)
        base[threadIdx.x] = atomicAdd(&counts[threadIdx.x], hist[threadIdx.x]);
    __syncthreads();
    if (lane == 0) {
        list[e1 * T_TOKENS + base[e1] + s1] = t * 2 + 0;   // token | slot bit
        list[e2 * T_TOKENS + base[e2] + s2] = t * 2 + 1;
    }
}

// ---------------------------------------------------------------- x -> bf16
__global__ __launch_bounds__(256) void k_cvt(const float* __restrict__ x,
                                             ushort_t* __restrict__ xb) {
    int n4 = T_TOKENS * D_DIM / 4;
    for (int j = blockIdx.x * 256 + threadIdx.x; j < n4; j += 256 * 256) {
        float4v v = ((const float4v*)x)[j];
        unsigned long long o =
            (unsigned long long)f2bf(v[0]) |
            ((unsigned long long)f2bf(v[1]) << 16) |
            ((unsigned long long)f2bf(v[2]) << 32) |
            ((unsigned long long)f2bf(v[3]) << 48);
        ((unsigned long long*)xb)[j] = o;
    }
}

// ---------------------------------------------------------------- finalize
__global__ void k_finalize(const int* __restrict__ counts, int* __restrict__ pcount,
                           int* __restrict__ offs, int* __restrict__ nrb,
                           int* __restrict__ rbmap) {
    if (threadIdx.x == 0) {
        int acc = 0, rb = 0;
        for (int e = 0; e < E_NUM; ++e) {
            int pc = (counts[e] + BM - 1) / BM * BM;
            pcount[e] = pc;
            offs[e] = acc;
            for (int i = 0; i < pc / BM; ++i) rbmap[rb++] = e;
            acc += pc;
        }
        nrb[0] = rb;
    }
}

// ---------------------------------------------------------------- compact
__global__ void k_compact(const int* __restrict__ counts, const int* __restrict__ pcount,
                          const int* __restrict__ offs, const int* __restrict__ list,
                          int* __restrict__ clist, int* __restrict__ rowOf) {
    int e = blockIdx.y;
    int s = blockIdx.x * 256 + threadIdx.x;
    if (s >= pcount[e]) return;
    int g = offs[e] + s;
    if (s < counts[e]) {
        int v = list[e * T_TOKENS + s];
        clist[g] = v >> 1;
        rowOf[v] = g;                 // v = tok*2 + slot
    } else {
        clist[g] = 0;                 // padding row gathers token 0 (output unused)
    }
}

// ---------------------------------------------------------------- up GEMM
__global__ void k_up_gemm(const ushort_t* __restrict__ xb, const ushort_t* __restrict__ wupT,
                          const float* __restrict__ b_up, const int* __restrict__ nrb,
                          const int* __restrict__ rbmap, const int* __restrict__ clist,
                          ushort_t* __restrict__ h) {
    int wg = blockIdx.x;
    int lin = (wg & 7) * (UP_BLOCKS / 8) + (wg >> 3);
    int nb = lin / RBMAX;
    int rb = lin % RBMAX;
    if (rb >= nrb[0]) return;
    int e = rbmap[rb];
    __shared__ __align__(16) ushort_t As[2][BM][BK];
    __shared__ __align__(16) ushort_t Bs[2][BN][BK];
    int t = threadIdx.x, wave = t >> 6, lane = t & 63;
    int wm = wave >> 1, wn = wave & 1;

    int row0 = rb * BM;
    int tokA0 = clist[row0 + (t >> 2)];
    int tokA1 = clist[row0 + 64 + (t >> 2)];
    const ushort_t* wb = wupT + (size_t)e * F_DIM * D_DIM + (size_t)(nb * BN) * D_DIM;

    float4v acc[4][4];
#pragma unroll
    for (int i = 0; i < 4; ++i)
#pragma unroll
        for (int j = 0; j < 4; ++j)
#pragma unroll
            for (int q = 0; q < 4; ++q) acc[i][j][q] = 0.f;

    int csw = (((t & 3) ^ ((t >> 3) & 3))) * 8;    // staged src chunk (swizzled)
    int swoff = (((lane >> 4) ^ (((lane & 15) >> 1) & 3))) * 8;  // read-side

    const ushort_t* gA0 = xb + (size_t)tokA0 * D_DIM + csw;
    const ushort_t* gA1 = xb + (size_t)tokA1 * D_DIM + csw;
    const ushort_t* gB0 = wb + (size_t)(t >> 2) * D_DIM + csw;
    const ushort_t* gB1 = wb + (size_t)(64 + (t >> 2)) * D_DIM + csw;

#define STAGE_UP(buf, kt) do { int k0 = (kt) * BK;                            \
        char* AsB = (char*)&As[buf][0][0]; char* BsB = (char*)&Bs[buf][0][0]; \
        GLOAD_LDS16(gA0 + k0, AsB + wave * 1024);                             \
        GLOAD_LDS16(gA1 + k0, AsB + 4096 + wave * 1024);                      \
        GLOAD_LDS16(gB0 + k0, BsB + wave * 1024);                             \
        GLOAD_LDS16(gB1 + k0, BsB + 4096 + wave * 1024); } while (0)

    STAGE_UP(0, 0);
    __syncthreads();
    const int nt = D_DIM / BK;
    for (int kt = 0; kt < nt; ++kt) {
        int buf = kt & 1;
        if (kt + 1 < nt) STAGE_UP(buf ^ 1, kt + 1);
        short8 af[4], bfr[4];
#pragma unroll
        for (int m = 0; m < 4; ++m)
            af[m] = *(const short8*)&As[buf][wm * 64 + m * 16 + (lane & 15)][swoff];
#pragma unroll
        for (int n = 0; n < 4; ++n)
            bfr[n] = *(const short8*)&Bs[buf][wn * 64 + n * 16 + (lane & 15)][swoff];
#pragma unroll
        for (int m = 0; m < 4; ++m)
#pragma unroll
            for (int n = 0; n < 4; ++n)
                acc[m][n] = __builtin_amdgcn_mfma_f32_16x16x32_bf16(af[m], bfr[n], acc[m][n], 0, 0, 0);
        __syncthreads();
    }

#pragma unroll
    for (int m = 0; m < 4; ++m) {
        int row_local = wm * 64 + m * 16 + (lane >> 4) * 4;
#pragma unroll
        for (int n = 0; n < 4; ++n) {
            int col = nb * BN + wn * 64 + n * 16 + (lane & 15);
            float bia = b_up[e * F_DIM + col];
#pragma unroll
            for (int j = 0; j < 4; ++j) {
                float v = acc[m][n][j] + bia;
                h[(size_t)(row0 + row_local + j) * F_DIM + col] = f2bf(gelu_fast(v));
            }
        }
    }
}

// ---------------------------------------------------------------- down GEMM
__global__ void k_down_gemm(const ushort_t* __restrict__ h, const ushort_t* __restrict__ wdT,
                            const float* __restrict__ b_down, const int* __restrict__ nrb,
                            const int* __restrict__ rbmap, float* __restrict__ yb) {
    int wg = blockIdx.x;
    int lin = (wg & 7) * (DN_BLOCKS / 8) + (wg >> 3);
    int nb = lin / (RBMAX * 2);
    int rbD = lin % (RBMAX * 2);
    if ((rbD >> 1) >= nrb[0]) return;
    int e = rbmap[rbD >> 1];
    __shared__ __align__(16) ushort_t As[2][DBM][BK];
    __shared__ __align__(16) ushort_t Bs[2][BN][BK];
    int t = threadIdx.x, wave = t >> 6, lane = t & 63;
    int wm = wave >> 1, wn = wave & 1;

    int row0 = rbD * DBM;
    const ushort_t* ha = h + (size_t)row0 * F_DIM;
    const ushort_t* wb = wdT + (size_t)e * D_DIM * F_DIM + (size_t)(nb * BN) * F_DIM;

    float4v acc[2][4];
#pragma unroll
    for (int i = 0; i < 2; ++i)
#pragma unroll
        for (int j = 0; j < 4; ++j)
#pragma unroll
            for (int q = 0; q < 4; ++q) acc[i][j][q] = 0.f;

    int csw = (((t & 3) ^ ((t >> 3) & 3))) * 8;
    int swoff = (((lane >> 4) ^ (((lane & 15) >> 1) & 3))) * 8;

    const ushort_t* gA0 = ha + (size_t)(t >> 2) * F_DIM + csw;
    const ushort_t* gB0 = wb + (size_t)(t >> 2) * F_DIM + csw;
    const ushort_t* gB1 = wb + (size_t)(64 + (t >> 2)) * F_DIM + csw;

#define STAGE_DN(buf, kt) do { int k0 = (kt) * BK;                            \
        char* AsB = (char*)&As[buf][0][0]; char* BsB = (char*)&Bs[buf][0][0]; \
        GLOAD_LDS16(gA0 + k0, AsB + wave * 1024);                             \
        GLOAD_LDS16(gB0 + k0, BsB + wave * 1024);                             \
        GLOAD_LDS16(gB1 + k0, BsB + 4096 + wave * 1024); } while (0)

    STAGE_DN(0, 0);
    __syncthreads();
    const int nt = F_DIM / BK;
    for (int kt = 0; kt < nt; ++kt) {
        int buf = kt & 1;
        if (kt + 1 < nt) STAGE_DN(buf ^ 1, kt + 1);
        short8 af[2], bfr[4];
#pragma unroll
        for (int m = 0; m < 2; ++m)
            af[m] = *(const short8*)&As[buf][wm * 32 + m * 16 + (lane & 15)][swoff];
#pragma unroll
        for (int n = 0; n < 4; ++n)
            bfr[n] = *(const short8*)&Bs[buf][wn * 64 + n * 16 + (lane & 15)][swoff];
#pragma unroll
        for (int m = 0; m < 2; ++m)
#pragma unroll
            for (int n = 0; n < 4; ++n)
                acc[m][n] = __builtin_amdgcn_mfma_f32_16x16x32_bf16(af[m], bfr[n], acc[m][n], 0, 0, 0);
        __syncthreads();
    }

#pragma unroll
    for (int m = 0; m < 2; ++m) {
        int row_local = wm * 32 + m * 16 + (lane >> 4) * 4;
#pragma unroll
        for (int n = 0; n < 4; ++n) {
            int col = nb * BN + wn * 64 + n * 16 + (lane & 15);
            float bia = b_down[e * D_DIM + col];
#pragma unroll
            for (int j = 0; j < 4; ++j) {
                yb[(size_t)(row0 + row_local + j) * D_DIM + col] = acc[m][n][j] + bia;
            }
        }
    }
}

// ---------------------------------------------------------------- combine
__global__ void k_combine(const float* __restrict__ yb, const int* __restrict__ rowOf,
                          const float* __restrict__ wsel, float* __restrict__ out) {
    int wave = threadIdx.x >> 6, lane = threadIdx.x & 63;
    int t = blockIdx.x * 4 + wave;
    int g0 = rowOf[t * 2], g1 = rowOf[t * 2 + 1];
    float w0 = wsel[t * 2], w1 = wsel[t * 2 + 1];
    const float4v* y0 = (const float4v*)(yb + (size_t)g0 * D_DIM);
    const float4v* y1 = (const float4v*)(yb + (size_t)g1 * D_DIM);
    float4v* o = (float4v*)(out + (size_t)t * D_DIM);
#pragma unroll
    for (int i = 0; i < 3; ++i) {
        int idx = lane + i * 64;
        float4v a = y0[idx], b = y1[idx];
        float4v r;
#pragma unroll
        for (int q = 0; q < 4; ++q) r[q] = w0 * a[q] + w1 * b[q];
        o[idx] = r;
    }
}

// ---------------------------------------------------------------- launch
extern "C" void kernel_launch(void* const* d_in, const int* in_sizes, int n_in,
                              void* d_out, int out_size, void* d_ws, size_t ws_size,
                              hipStream_t stream) {
    const float* x   = (const float*)d_in[0];   // [2,2048,768]
    const float* gw  = (const float*)d_in[1];   // [768,8]
    const float* wup = (const float*)d_in[2];   // [8,768,3072]
    const float* bup = (const float*)d_in[3];   // [8,3072]
    const float* wdn = (const float*)d_in[4];   // [8,3072,768]
    const float* bdn = (const float*)d_in[5];   // [8,768]
    float* out = (float*)d_out;

    char* ws = (char*)d_ws;
    int*   counts = (int*)(ws);
    int*   pcount = (int*)(ws + 32);
    int*   offs   = (int*)(ws + 64);
    int*   nrb    = (int*)(ws + 96);
    int*   rbmap  = (int*)(ws + 128);
    int*   list   = (int*)(ws + 1024);
    size_t p = 1024 + (size_t)E_NUM * T_TOKENS * 4;
    int*   clist  = (int*)(ws + p); p += (size_t)(RBMAX * BM) * 4;
    int*   rowOf  = (int*)(ws + p); p += (size_t)T_TOKENS * 2 * 4;
    float* wsel   = (float*)(ws + p); p += (size_t)T_TOKENS * 2 * 4;
    p = (p + 255) & ~(size_t)255;
    size_t p_xb = p;
    ushort_t* xb   = (ushort_t*)(ws + p); p += (size_t)T_TOKENS * D_DIM * 2;
    ushort_t* wupT = (ushort_t*)(ws + p); p += (size_t)E_NUM * D_DIM * F_DIM * 2;
    ushort_t* wdnT = (ushort_t*)(ws + p); p += (size_t)E_NUM * D_DIM * F_DIM * 2;
    ushort_t* hbuf = (ushort_t*)(ws + p); p += (size_t)(RBMAX * BM) * F_DIM * 2;
    // ybuf aliases xb+wupT (both dead once down GEMM runs): 28.3MB <= 43.5MB
    float* ybuf = (float*)(ws + p_xb);

    hipMemsetAsync(counts, 0, E_NUM * sizeof(int), stream);
    k_gate<<<T_TOKENS / 16, 1024, 0, stream>>>(x, gw, counts, list, wsel);
    k_trans<<<TRT_TOT / 4, 256, 0, stream>>>(wup, wdn, wupT, wdnT);
    k_cvt<<<256, 256, 0, stream>>>(x, xb);
    k_finalize<<<1, 64, 0, stream>>>(counts, pcount, offs, nrb, rbmap);
    k_compact<<<dim3(T_TOKENS / 256, E_NUM), 256, 0, stream>>>(
        counts, pcount, offs, list, clist, rowOf);
    k_up_gemm<<<UP_BLOCKS, 256, 0, stream>>>(
        xb, wupT, bup, nrb, rbmap, clist, hbuf);
    k_down_gemm<<<DN_BLOCKS, 256, 0, stream>>>(
        hbuf, wdnT, bdn, nrb, rbmap, ybuf);
    k_combine<<<T_TOKENS / 4, 256, 0, stream>>>(ybuf, rowOf, wsel, out);
}

// Round 10
// 227.938 us; speedup vs baseline: 1.8529x; 1.0292x over previous
//
#include <hip/hip_runtime.h>
#include <hip/hip_bf16.h>
#include <math.h>

// Problem constants (B=2,S=2048 -> T=4096 tokens)
#define T_TOKENS 4096
#define D_DIM 768
#define F_DIM 3072
#define E_NUM 8

#define BM 128
#define BN 128
#define BK 32
#define RBMAX 72                 // max padded 128-row blocks
#define NBU (F_DIM / BN)         // 24
#define NBD (D_DIM / BN)         // 6
#define UP_BLOCKS (NBU * RBMAX)  // 1728
#define DBM 64                   // down-GEMM row-tile
#define KHALF (F_DIM / 2)        // 1536: down split-K chunk
#define DN_BLOCKS (NBD * RBMAX * 2 * 2)  // 1728 (nb x rbD x kc)
#define GROWS (RBMAX * BM)       // 9216 padded rows

#define TILE_LDS (64 * 66)       // bf16 elems per wave-private transpose tile
#define TRT_WUP 4608             // 64x64 tiles in wup
#define TRT_TOT 9216             // + wdn

typedef __attribute__((ext_vector_type(8))) short short8;
typedef __attribute__((ext_vector_type(4))) short short4v;
typedef __attribute__((ext_vector_type(4))) float float4v;
typedef unsigned short ushort_t;
typedef unsigned long long ull_t;

__device__ __forceinline__ ushort_t f2bf(float f) {
    union { float f; unsigned u; } v; v.f = f;
    unsigned r = v.u + 0x7fffu + ((v.u >> 16) & 1u);   // RNE
    return (ushort_t)(r >> 16);
}

__device__ __forceinline__ float bf2f(ushort_t u) {
    union { unsigned u; float f; } v; v.u = ((unsigned)u) << 16;
    return v.f;
}

__device__ __forceinline__ float gelu_fast(float v) {
    float u = v + 0.044715f * v * v * v;
    return v / (1.f + __expf(-1.5957691216f * u));
}

#define GLOAD_LDS16(gp, lp) __builtin_amdgcn_global_load_lds( \
    (const __attribute__((address_space(1))) void*)(gp),      \
    (__attribute__((address_space(3))) void*)(lp), 16, 0, 0)

// expert for padded 128-row block rb, plus total block count
__device__ __forceinline__ int rb_expert(const int* __restrict__ counts,
                                         int rb, int& total) {
    int e = 0, acc = 0;
#pragma unroll
    for (int ee = 0; ee < E_NUM; ++ee) {
        int nbe = (counts[ee] + BM - 1) / BM;
        if (rb >= acc && rb < acc + nbe) e = ee;
        acc += nbe;
    }
    total = acc;
    return e;
}

// ---------------------------------------------------------------- tile coords
__device__ __forceinline__ void tile_coords(int g, int R, int C,
                                            int& e, int& r0, int& c0) {
    int tpr = C / 64, tpc = R / 64;
    e = g / (tpr * tpc);
    int rem = g % (tpr * tpc);
    r0 = (rem / tpr) * 64;
    c0 = (rem % tpr) * 64;
}

// ------------------------------------------------- per-WAVE barrier-free transpose
__device__ __forceinline__ void wave_transpose64(const float* __restrict__ ip,
                                                 ushort_t* __restrict__ op,
                                                 int R, int C, int r0, int c0,
                                                 ushort_t* __restrict__ tl) {
    int l = threadIdx.x & 63;
    int lr = l >> 4;             // 0..3
    int lc4 = (l & 15) * 4;      // 0,4,...,60

    float4v v[16];
#pragma unroll
    for (int i = 0; i < 16; ++i)
        v[i] = *(const float4v*)&ip[(size_t)(r0 + 4 * i + lr) * C + c0 + lc4];
#pragma unroll
    for (int i = 0; i < 16; ++i) {
        short4v s = { (short)f2bf(v[i][0]), (short)f2bf(v[i][1]),
                      (short)f2bf(v[i][2]), (short)f2bf(v[i][3]) };
        *(short4v*)&tl[(4 * i + lr) * 66 + lc4] = s;
    }
    asm volatile("s_waitcnt lgkmcnt(0)" ::: "memory");
#pragma unroll
    for (int i = 0; i < 16; ++i) {
        int rr = 4 * i + lr;                     // output row (= orig col c0+rr)
        short4v s = { (short)tl[(lc4 + 0) * 66 + rr],
                      (short)tl[(lc4 + 1) * 66 + rr],
                      (short)tl[(lc4 + 2) * 66 + rr],
                      (short)tl[(lc4 + 3) * 66 + rr] };
        *(short4v*)&op[(size_t)(c0 + rr) * R + r0 + lc4] = s;
    }
}

// ---------------------------------------------------------------- transpose kernel
__global__ __launch_bounds__(256) void k_trans(const float* __restrict__ wup,
                                               const float* __restrict__ wdn,
                                               ushort_t* __restrict__ wupT,
                                               ushort_t* __restrict__ wdnT) {
    __shared__ ushort_t ttile[4][TILE_LDS];
    int wave = threadIdx.x >> 6;
    int g = blockIdx.x * 4 + wave;               // 0..9215
    const float* in; ushort_t* outp; int R, C;
    if (g < TRT_WUP) { in = wup; outp = wupT; R = D_DIM; C = F_DIM; }
    else { g -= TRT_WUP; in = wdn; outp = wdnT; R = F_DIM; C = D_DIM; }
    int e, r0, c0;
    tile_coords(g, R, C, e, r0, c0);
    wave_transpose64(in + (size_t)e * R * C, outp + (size_t)e * R * C,
                     R, C, r0, c0, &ttile[wave][0]);
}

// ---------------------------------------------------------------- gate (+ x->bf16)
// 16 tokens/block; single x pass feeds both logits and bf16 conversion;
// LDS histogram -> 8 global atomics per block.
__global__ __launch_bounds__(1024) void k_gate(const float* __restrict__ x,
                                               const float* __restrict__ gw,
                                               int* __restrict__ counts,
                                               int* __restrict__ list,
                                               float* __restrict__ wsel,
                                               ushort_t* __restrict__ xb) {
    __shared__ int hist[E_NUM];
    __shared__ int base[E_NUM];
    int wave = threadIdx.x >> 6, lane = threadIdx.x & 63;
    int t = blockIdx.x * 16 + wave;

    float acc[E_NUM];
#pragma unroll
    for (int e = 0; e < E_NUM; ++e) acc[e] = 0.f;
    const float4v* xr4 = (const float4v*)(x + (size_t)t * D_DIM);
    ull_t* xbr = (ull_t*)(xb + (size_t)t * D_DIM);
#pragma unroll
    for (int i = 0; i < 3; ++i) {
        int j = lane + i * 64;                   // float4 index within row
        float4v v = xr4[j];
        xbr[j] = (ull_t)f2bf(v[0]) | ((ull_t)f2bf(v[1]) << 16) |
                 ((ull_t)f2bf(v[2]) << 32) | ((ull_t)f2bf(v[3]) << 48);
        int d0 = 4 * j;
#pragma unroll
        for (int q = 0; q < 4; ++q) {
            const float* g = gw + (size_t)(d0 + q) * E_NUM;
#pragma unroll
            for (int e = 0; e < E_NUM; ++e) acc[e] += v[q] * g[e];
        }
    }
#pragma unroll
    for (int e = 0; e < E_NUM; ++e) {
#pragma unroll
        for (int s = 32; s >= 1; s >>= 1) acc[e] += __shfl_xor(acc[e], s);
    }

    if (threadIdx.x < E_NUM) hist[threadIdx.x] = 0;
    __syncthreads();

    int e1 = 0, e2 = 0, s1 = 0, s2 = 0;
    if (lane == 0) {
        float mx = acc[0];
#pragma unroll
        for (int e = 1; e < E_NUM; ++e) mx = fmaxf(mx, acc[e]);
        float p[E_NUM], sum = 0.f;
#pragma unroll
        for (int e = 0; e < E_NUM; ++e) { p[e] = expf(acc[e] - mx); sum += p[e]; }
        float inv = 1.f / sum;
#pragma unroll
        for (int e = 0; e < E_NUM; ++e) p[e] *= inv;
#pragma unroll
        for (int e = 1; e < E_NUM; ++e) if (p[e] > p[e1]) e1 = e;
        e2 = (e1 == 0) ? 1 : 0;
#pragma unroll
        for (int e = 0; e < E_NUM; ++e) if (e != e1 && p[e] > p[e2]) e2 = e;
        s1 = atomicAdd(&hist[e1], 1);            // LDS atomic
        s2 = atomicAdd(&hist[e2], 1);
        wsel[t * 2 + 0] = p[e1];
        wsel[t * 2 + 1] = p[e2];
    }
    __syncthreads();
    if (threadIdx.x < E_NUM)
        base[threadIdx.x] = atomicAdd(&counts[threadIdx.x], hist[threadIdx.x]);
    __syncthreads();
    if (lane == 0) {
        list[e1 * T_TOKENS + base[e1] + s1] = t * 2 + 0;   // token | slot bit
        list[e2 * T_TOKENS + base[e2] + s2] = t * 2 + 1;
    }
}

// ---------------------------------------------------------------- compact
// offsets derived inline from counts (no finalize kernel)
__global__ void k_compact(const int* __restrict__ counts, const int* __restrict__ list,
                          int* __restrict__ clist, int* __restrict__ rowOf) {
    int e = blockIdx.y;
    int s = blockIdx.x * 256 + threadIdx.x;
    int off = 0, cnt = 0;
#pragma unroll
    for (int ee = 0; ee < E_NUM; ++ee) {
        int c = counts[ee];
        int pc = (c + BM - 1) / BM * BM;
        if (ee < e) off += pc;
        if (ee == e) cnt = c;
    }
    int pcnt = (cnt + BM - 1) / BM * BM;
    if (s >= pcnt) return;
    int g = off + s;
    if (s < cnt) {
        int v = list[e * T_TOKENS + s];
        clist[g] = v >> 1;
        rowOf[v] = g;                 // v = tok*2 + slot
    } else {
        clist[g] = 0;                 // padding row gathers token 0 (output unused)
    }
}

// ---------------------------------------------------------------- up GEMM
__global__ void k_up_gemm(const ushort_t* __restrict__ xb, const ushort_t* __restrict__ wupT,
                          const float* __restrict__ b_up, const int* __restrict__ counts,
                          const int* __restrict__ clist, ushort_t* __restrict__ h) {
    int wg = blockIdx.x;
    int lin = (wg & 7) * (UP_BLOCKS / 8) + (wg >> 3);
    int nb = lin / RBMAX;
    int rb = lin % RBMAX;
    int total;
    int e = rb_expert(counts, rb, total);
    if (rb >= total) return;
    __shared__ __align__(16) ushort_t As[2][BM][BK];
    __shared__ __align__(16) ushort_t Bs[2][BN][BK];
    int t = threadIdx.x, wave = t >> 6, lane = t & 63;
    int wm = wave >> 1, wn = wave & 1;

    int row0 = rb * BM;
    int tokA0 = clist[row0 + (t >> 2)];
    int tokA1 = clist[row0 + 64 + (t >> 2)];
    const ushort_t* wb = wupT + (size_t)e * F_DIM * D_DIM + (size_t)(nb * BN) * D_DIM;

    float4v acc[4][4];
#pragma unroll
    for (int i = 0; i < 4; ++i)
#pragma unroll
        for (int j = 0; j < 4; ++j)
#pragma unroll
            for (int q = 0; q < 4; ++q) acc[i][j][q] = 0.f;

    int csw = (((t & 3) ^ ((t >> 3) & 3))) * 8;    // staged src chunk (swizzled)
    int swoff = (((lane >> 4) ^ (((lane & 15) >> 1) & 3))) * 8;  // read-side

    const ushort_t* gA0 = xb + (size_t)tokA0 * D_DIM + csw;
    const ushort_t* gA1 = xb + (size_t)tokA1 * D_DIM + csw;
    const ushort_t* gB0 = wb + (size_t)(t >> 2) * D_DIM + csw;
    const ushort_t* gB1 = wb + (size_t)(64 + (t >> 2)) * D_DIM + csw;

#define STAGE_UP(buf, kt) do { int k0 = (kt) * BK;                            \
        char* AsB = (char*)&As[buf][0][0]; char* BsB = (char*)&Bs[buf][0][0]; \
        GLOAD_LDS16(gA0 + k0, AsB + wave * 1024);                             \
        GLOAD_LDS16(gA1 + k0, AsB + 4096 + wave * 1024);                      \
        GLOAD_LDS16(gB0 + k0, BsB + wave * 1024);                             \
        GLOAD_LDS16(gB1 + k0, BsB + 4096 + wave * 1024); } while (0)

    STAGE_UP(0, 0);
    __syncthreads();
    const int nt = D_DIM / BK;
    for (int kt = 0; kt < nt; ++kt) {
        int buf = kt & 1;
        if (kt + 1 < nt) STAGE_UP(buf ^ 1, kt + 1);
        short8 af[4], bfr[4];
#pragma unroll
        for (int m = 0; m < 4; ++m)
            af[m] = *(const short8*)&As[buf][wm * 64 + m * 16 + (lane & 15)][swoff];
#pragma unroll
        for (int n = 0; n < 4; ++n)
            bfr[n] = *(const short8*)&Bs[buf][wn * 64 + n * 16 + (lane & 15)][swoff];
#pragma unroll
        for (int m = 0; m < 4; ++m)
#pragma unroll
            for (int n = 0; n < 4; ++n)
                acc[m][n] = __builtin_amdgcn_mfma_f32_16x16x32_bf16(af[m], bfr[n], acc[m][n], 0, 0, 0);
        __syncthreads();
    }

#pragma unroll
    for (int m = 0; m < 4; ++m) {
        int row_local = wm * 64 + m * 16 + (lane >> 4) * 4;
#pragma unroll
        for (int n = 0; n < 4; ++n) {
            int col = nb * BN + wn * 64 + n * 16 + (lane & 15);
            float bia = b_up[e * F_DIM + col];
#pragma unroll
            for (int j = 0; j < 4; ++j) {
                float v = acc[m][n][j] + bia;
                h[(size_t)(row0 + row_local + j) * F_DIM + col] = f2bf(gelu_fast(v));
            }
        }
    }
}

// ---------------------------------------------------------------- down GEMM
// split-K x2, 64x128 tile, bf16 partial stores into ybuf[kc] (no atomics)
__global__ void k_down_gemm(const ushort_t* __restrict__ h, const ushort_t* __restrict__ wdT,
                            const float* __restrict__ b_down, const int* __restrict__ counts,
                            ushort_t* __restrict__ yb) {
    int wg = blockIdx.x;
    int lin = (wg & 7) * (DN_BLOCKS / 8) + (wg >> 3);
    int nbkc = lin / (RBMAX * 2);      // 0..11  (nb,kc)-outer
    int rbD = lin % (RBMAX * 2);       // rbD-inner: h rows hot per XCD chunk
    int nb = nbkc >> 1, kc = nbkc & 1;
    int rb = rbD >> 1;
    int total;
    int e = rb_expert(counts, rb, total);
    if (rb >= total) return;
    __shared__ __align__(16) ushort_t As[2][DBM][BK];
    __shared__ __align__(16) ushort_t Bs[2][BN][BK];
    int t = threadIdx.x, wave = t >> 6, lane = t & 63;
    int wm = wave >> 1, wn = wave & 1;

    int row0 = rbD * DBM;
    int kbase = kc * KHALF;
    const ushort_t* ha = h + (size_t)row0 * F_DIM + kbase;
    const ushort_t* wb = wdT + (size_t)e * D_DIM * F_DIM + (size_t)(nb * BN) * F_DIM + kbase;

    float4v acc[2][4];
#pragma unroll
    for (int i = 0; i < 2; ++i)
#pragma unroll
        for (int j = 0; j < 4; ++j)
#pragma unroll
            for (int q = 0; q < 4; ++q) acc[i][j][q] = 0.f;

    int csw = (((t & 3) ^ ((t >> 3) & 3))) * 8;
    int swoff = (((lane >> 4) ^ (((lane & 15) >> 1) & 3))) * 8;

    const ushort_t* gA0 = ha + (size_t)(t >> 2) * F_DIM + csw;
    const ushort_t* gB0 = wb + (size_t)(t >> 2) * F_DIM + csw;
    const ushort_t* gB1 = wb + (size_t)(64 + (t >> 2)) * F_DIM + csw;

#define STAGE_DN(buf, kt) do { int k0 = (kt) * BK;                            \
        char* AsB = (char*)&As[buf][0][0]; char* BsB = (char*)&Bs[buf][0][0]; \
        GLOAD_LDS16(gA0 + k0, AsB + wave * 1024);                             \
        GLOAD_LDS16(gB0 + k0, BsB + wave * 1024);                             \
        GLOAD_LDS16(gB1 + k0, BsB + 4096 + wave * 1024); } while (0)

    STAGE_DN(0, 0);
    __syncthreads();
    const int nt = KHALF / BK;
    for (int kt = 0; kt < nt; ++kt) {
        int buf = kt & 1;
        if (kt + 1 < nt) STAGE_DN(buf ^ 1, kt + 1);
        short8 af[2], bfr[4];
#pragma unroll
        for (int m = 0; m < 2; ++m)
            af[m] = *(const short8*)&As[buf][wm * 32 + m * 16 + (lane & 15)][swoff];
#pragma unroll
        for (int n = 0; n < 4; ++n)
            bfr[n] = *(const short8*)&Bs[buf][wn * 64 + n * 16 + (lane & 15)][swoff];
#pragma unroll
        for (int m = 0; m < 2; ++m)
#pragma unroll
            for (int n = 0; n < 4; ++n)
                acc[m][n] = __builtin_amdgcn_mfma_f32_16x16x32_bf16(af[m], bfr[n], acc[m][n], 0, 0, 0);
        __syncthreads();
    }

    ushort_t* ybk = yb + (size_t)kc * GROWS * D_DIM;
#pragma unroll
    for (int m = 0; m < 2; ++m) {
        int row_local = wm * 32 + m * 16 + (lane >> 4) * 4;
#pragma unroll
        for (int n = 0; n < 4; ++n) {
            int col = nb * BN + wn * 64 + n * 16 + (lane & 15);
            float bia = (kc == 0) ? b_down[e * D_DIM + col] : 0.f;
#pragma unroll
            for (int j = 0; j < 4; ++j) {
                ybk[(size_t)(row0 + row_local + j) * D_DIM + col] =
                    f2bf(acc[m][n][j] + bia);
            }
        }
    }
}

// ---------------------------------------------------------------- combine
// out[t] = w0*(y[0][g0]+y[1][g0]) + w1*(y[0][g1]+y[1][g1])
__global__ void k_combine(const ushort_t* __restrict__ yb, const int* __restrict__ rowOf,
                          const float* __restrict__ wsel, float* __restrict__ out) {
    int wave = threadIdx.x >> 6, lane = threadIdx.x & 63;
    int t = blockIdx.x * 4 + wave;
    int g0 = rowOf[t * 2], g1 = rowOf[t * 2 + 1];
    float w0 = wsel[t * 2], w1 = wsel[t * 2 + 1];
    const ushort_t* a0 = yb + (size_t)g0 * D_DIM;
    const ushort_t* a1 = yb + ((size_t)GROWS + g0) * D_DIM;
    const ushort_t* b0 = yb + (size_t)g1 * D_DIM;
    const ushort_t* b1 = yb + ((size_t)GROWS + g1) * D_DIM;
    float4v* o = (float4v*)(out + (size_t)t * D_DIM);
#pragma unroll
    for (int i = 0; i < 3; ++i) {
        int idx = (lane + i * 64) * 4;
        short4v va0 = *(const short4v*)&a0[idx];
        short4v va1 = *(const short4v*)&a1[idx];
        short4v vb0 = *(const short4v*)&b0[idx];
        short4v vb1 = *(const short4v*)&b1[idx];
        float4v r;
#pragma unroll
        for (int q = 0; q < 4; ++q)
            r[q] = w0 * (bf2f((ushort_t)va0[q]) + bf2f((ushort_t)va1[q]))
                 + w1 * (bf2f((ushort_t)vb0[q]) + bf2f((ushort_t)vb1[q]));
        o[(lane + i * 64)] = r;
    }
}

// ---------------------------------------------------------------- launch
extern "C" void kernel_launch(void* const* d_in, const int* in_sizes, int n_in,
                              void* d_out, int out_size, void* d_ws, size_t ws_size,
                              hipStream_t stream) {
    const float* x   = (const float*)d_in[0];   // [2,2048,768]
    const float* gw  = (const float*)d_in[1];   // [768,8]
    const float* wup = (const float*)d_in[2];   // [8,768,3072]
    const float* bup = (const float*)d_in[3];   // [8,3072]
    const float* wdn = (const float*)d_in[4];   // [8,3072,768]
    const float* bdn = (const float*)d_in[5];   // [8,768]
    float* out = (float*)d_out;

    char* ws = (char*)d_ws;
    int*   counts = (int*)(ws);
    int*   list   = (int*)(ws + 1024);
    size_t p = 1024 + (size_t)E_NUM * T_TOKENS * 4;
    int*   clist  = (int*)(ws + p); p += (size_t)GROWS * 4;
    int*   rowOf  = (int*)(ws + p); p += (size_t)T_TOKENS * 2 * 4;
    float* wsel   = (float*)(ws + p); p += (size_t)T_TOKENS * 2 * 4;
    p = (p + 255) & ~(size_t)255;
    size_t p_xb = p;
    ushort_t* xb   = (ushort_t*)(ws + p); p += (size_t)T_TOKENS * D_DIM * 2;
    ushort_t* wupT = (ushort_t*)(ws + p); p += (size_t)E_NUM * D_DIM * F_DIM * 2;
    ushort_t* wdnT = (ushort_t*)(ws + p); p += (size_t)E_NUM * D_DIM * F_DIM * 2;
    ushort_t* hbuf = (ushort_t*)(ws + p); p += (size_t)GROWS * F_DIM * 2;
    // ybuf (2 planes bf16, 28.3MB) aliases xb+wupT (44MB, dead after up GEMM)
    ushort_t* ybuf = (ushort_t*)(ws + p_xb);

    hipMemsetAsync(counts, 0, E_NUM * sizeof(int), stream);
    k_gate<<<T_TOKENS / 16, 1024, 0, stream>>>(x, gw, counts, list, wsel, xb);
    k_trans<<<TRT_TOT / 4, 256, 0, stream>>>(wup, wdn, wupT, wdnT);
    k_compact<<<dim3(17, E_NUM), 256, 0, stream>>>(counts, list, clist, rowOf);
    k_up_gemm<<<UP_BLOCKS, 256, 0, stream>>>(xb, wupT, bup, counts, clist, hbuf);
    k_down_gemm<<<DN_BLOCKS, 256, 0, stream>>>(hbuf, wdnT, bdn, counts, ybuf);
    k_combine<<<T_TOKENS / 4, 256, 0, stream>>>(ybuf, rowOf, wsel, out);
}

// Round 11
// 224.277 us; speedup vs baseline: 1.8832x; 1.0163x over previous
//
#include <hip/hip_runtime.h>
#include <hip/hip_bf16.h>
#include <math.h>

// Problem constants (B=2,S=2048 -> T=4096 tokens)
#define T_TOKENS 4096
#define D_DIM 768
#define F_DIM 3072
#define E_NUM 8

#define BM 128
#define BN 128
#define BK 32
#define RBMAX 72                 // max padded 128-row blocks
#define NBU (F_DIM / BN)         // 24
#define NBD (D_DIM / BN)         // 6
#define UP_BLOCKS (NBU * RBMAX)  // 1728
#define KHALF (F_DIM / 2)        // 1536: down split-K chunk
#define DN_BLOCKS (NBD * RBMAX * 2)  // 864 (nb x kc x rb), BM=128 tiles
#define GROWS (RBMAX * BM)       // 9216 padded rows

#define TILE_LDS (64 * 66)       // bf16 elems per wave-private transpose tile
#define TRT_WUP 4608             // 64x64 tiles in wup
#define TRT_TOT 9216             // + wdn

typedef __attribute__((ext_vector_type(8))) short short8;
typedef __attribute__((ext_vector_type(4))) short short4v;
typedef __attribute__((ext_vector_type(4))) float float4v;
typedef unsigned short ushort_t;
typedef unsigned long long ull_t;

__device__ __forceinline__ ushort_t f2bf(float f) {
    union { float f; unsigned u; } v; v.f = f;
    unsigned r = v.u + 0x7fffu + ((v.u >> 16) & 1u);   // RNE
    return (ushort_t)(r >> 16);
}

__device__ __forceinline__ float bf2f(ushort_t u) {
    union { unsigned u; float f; } v; v.u = ((unsigned)u) << 16;
    return v.f;
}

__device__ __forceinline__ float gelu_fast(float v) {
    float u = v + 0.044715f * v * v * v;
    return v / (1.f + __expf(-1.5957691216f * u));
}

#define GLOAD_LDS16(gp, lp) __builtin_amdgcn_global_load_lds( \
    (const __attribute__((address_space(1))) void*)(gp),      \
    (__attribute__((address_space(3))) void*)(lp), 16, 0, 0)

// expert for padded 128-row block rb, plus total block count
__device__ __forceinline__ int rb_expert(const int* __restrict__ counts,
                                         int rb, int& total) {
    int e = 0, acc = 0;
#pragma unroll
    for (int ee = 0; ee < E_NUM; ++ee) {
        int nbe = (counts[ee] + BM - 1) / BM;
        if (rb >= acc && rb < acc + nbe) e = ee;
        acc += nbe;
    }
    total = acc;
    return e;
}

// ---------------------------------------------------------------- tile coords
__device__ __forceinline__ void tile_coords(int g, int R, int C,
                                            int& e, int& r0, int& c0) {
    int tpr = C / 64, tpc = R / 64;
    e = g / (tpr * tpc);
    int rem = g % (tpr * tpc);
    r0 = (rem / tpr) * 64;
    c0 = (rem % tpr) * 64;
}

// ------------------------------------------------- per-WAVE barrier-free transpose
__device__ __forceinline__ void wave_transpose64(const float* __restrict__ ip,
                                                 ushort_t* __restrict__ op,
                                                 int R, int C, int r0, int c0,
                                                 ushort_t* __restrict__ tl) {
    int l = threadIdx.x & 63;
    int lr = l >> 4;             // 0..3
    int lc4 = (l & 15) * 4;      // 0,4,...,60

    float4v v[16];
#pragma unroll
    for (int i = 0; i < 16; ++i)
        v[i] = *(const float4v*)&ip[(size_t)(r0 + 4 * i + lr) * C + c0 + lc4];
#pragma unroll
    for (int i = 0; i < 16; ++i) {
        short4v s = { (short)f2bf(v[i][0]), (short)f2bf(v[i][1]),
                      (short)f2bf(v[i][2]), (short)f2bf(v[i][3]) };
        *(short4v*)&tl[(4 * i + lr) * 66 + lc4] = s;
    }
    asm volatile("s_waitcnt lgkmcnt(0)" ::: "memory");
#pragma unroll
    for (int i = 0; i < 16; ++i) {
        int rr = 4 * i + lr;                     // output row (= orig col c0+rr)
        short4v s = { (short)tl[(lc4 + 0) * 66 + rr],
                      (short)tl[(lc4 + 1) * 66 + rr],
                      (short)tl[(lc4 + 2) * 66 + rr],
                      (short)tl[(lc4 + 3) * 66 + rr] };
        *(short4v*)&op[(size_t)(c0 + rr) * R + r0 + lc4] = s;
    }
}

// ---------------------------------------------------------------- transpose kernel
__global__ __launch_bounds__(256) void k_trans(const float* __restrict__ wup,
                                               const float* __restrict__ wdn,
                                               ushort_t* __restrict__ wupT,
                                               ushort_t* __restrict__ wdnT) {
    __shared__ ushort_t ttile[4][TILE_LDS];
    int wave = threadIdx.x >> 6;
    int g = blockIdx.x * 4 + wave;               // 0..9215
    const float* in; ushort_t* outp; int R, C;
    if (g < TRT_WUP) { in = wup; outp = wupT; R = D_DIM; C = F_DIM; }
    else { g -= TRT_WUP; in = wdn; outp = wdnT; R = F_DIM; C = D_DIM; }
    int e, r0, c0;
    tile_coords(g, R, C, e, r0, c0);
    wave_transpose64(in + (size_t)e * R * C, outp + (size_t)e * R * C,
                     R, C, r0, c0, &ttile[wave][0]);
}

// ---------------------------------------------------------------- gate (+ x->bf16)
__global__ __launch_bounds__(1024) void k_gate(const float* __restrict__ x,
                                               const float* __restrict__ gw,
                                               int* __restrict__ counts,
                                               int* __restrict__ list,
                                               float* __restrict__ wsel,
                                               ushort_t* __restrict__ xb) {
    __shared__ int hist[E_NUM];
    __shared__ int base[E_NUM];
    int wave = threadIdx.x >> 6, lane = threadIdx.x & 63;
    int t = blockIdx.x * 16 + wave;

    float acc[E_NUM];
#pragma unroll
    for (int e = 0; e < E_NUM; ++e) acc[e] = 0.f;
    const float4v* xr4 = (const float4v*)(x + (size_t)t * D_DIM);
    ull_t* xbr = (ull_t*)(xb + (size_t)t * D_DIM);
#pragma unroll
    for (int i = 0; i < 3; ++i) {
        int j = lane + i * 64;                   // float4 index within row
        float4v v = xr4[j];
        xbr[j] = (ull_t)f2bf(v[0]) | ((ull_t)f2bf(v[1]) << 16) |
                 ((ull_t)f2bf(v[2]) << 32) | ((ull_t)f2bf(v[3]) << 48);
        int d0 = 4 * j;
#pragma unroll
        for (int q = 0; q < 4; ++q) {
            const float* g = gw + (size_t)(d0 + q) * E_NUM;
#pragma unroll
            for (int e = 0; e < E_NUM; ++e) acc[e] += v[q] * g[e];
        }
    }
#pragma unroll
    for (int e = 0; e < E_NUM; ++e) {
#pragma unroll
        for (int s = 32; s >= 1; s >>= 1) acc[e] += __shfl_xor(acc[e], s);
    }

    if (threadIdx.x < E_NUM) hist[threadIdx.x] = 0;
    __syncthreads();

    int e1 = 0, e2 = 0, s1 = 0, s2 = 0;
    if (lane == 0) {
        float mx = acc[0];
#pragma unroll
        for (int e = 1; e < E_NUM; ++e) mx = fmaxf(mx, acc[e]);
        float p[E_NUM], sum = 0.f;
#pragma unroll
        for (int e = 0; e < E_NUM; ++e) { p[e] = expf(acc[e] - mx); sum += p[e]; }
        float inv = 1.f / sum;
#pragma unroll
        for (int e = 0; e < E_NUM; ++e) p[e] *= inv;
#pragma unroll
        for (int e = 1; e < E_NUM; ++e) if (p[e] > p[e1]) e1 = e;
        e2 = (e1 == 0) ? 1 : 0;
#pragma unroll
        for (int e = 0; e < E_NUM; ++e) if (e != e1 && p[e] > p[e2]) e2 = e;
        s1 = atomicAdd(&hist[e1], 1);            // LDS atomic
        s2 = atomicAdd(&hist[e2], 1);
        wsel[t * 2 + 0] = p[e1];
        wsel[t * 2 + 1] = p[e2];
    }
    __syncthreads();
    if (threadIdx.x < E_NUM)
        base[threadIdx.x] = atomicAdd(&counts[threadIdx.x], hist[threadIdx.x]);
    __syncthreads();
    if (lane == 0) {
        list[e1 * T_TOKENS + base[e1] + s1] = t * 2 + 0;   // token | slot bit
        list[e2 * T_TOKENS + base[e2] + s2] = t * 2 + 1;
    }
}

// ---------------------------------------------------------------- compact
__global__ void k_compact(const int* __restrict__ counts, const int* __restrict__ list,
                          int* __restrict__ clist, int* __restrict__ rowOf) {
    int e = blockIdx.y;
    int s = blockIdx.x * 256 + threadIdx.x;
    int off = 0, cnt = 0;
#pragma unroll
    for (int ee = 0; ee < E_NUM; ++ee) {
        int c = counts[ee];
        int pc = (c + BM - 1) / BM * BM;
        if (ee < e) off += pc;
        if (ee == e) cnt = c;
    }
    int pcnt = (cnt + BM - 1) / BM * BM;
    if (s >= pcnt) return;
    int g = off + s;
    if (s < cnt) {
        int v = list[e * T_TOKENS + s];
        clist[g] = v >> 1;
        rowOf[v] = g;                 // v = tok*2 + slot
    } else {
        clist[g] = 0;                 // padding row gathers token 0 (output unused)
    }
}

// ---------------------------------------------------------------- up GEMM
__global__ void k_up_gemm(const ushort_t* __restrict__ xb, const ushort_t* __restrict__ wupT,
                          const float* __restrict__ b_up, const int* __restrict__ counts,
                          const int* __restrict__ clist, ushort_t* __restrict__ h) {
    int wg = blockIdx.x;
    int lin = (wg & 7) * (UP_BLOCKS / 8) + (wg >> 3);
    int nb = lin / RBMAX;
    int rb = lin % RBMAX;
    int total;
    int e = rb_expert(counts, rb, total);
    if (rb >= total) return;
    __shared__ __align__(16) ushort_t As[2][BM][BK];
    __shared__ __align__(16) ushort_t Bs[2][BN][BK];
    int t = threadIdx.x, wave = t >> 6, lane = t & 63;
    int wm = wave >> 1, wn = wave & 1;

    int row0 = rb * BM;
    int tokA0 = clist[row0 + (t >> 2)];
    int tokA1 = clist[row0 + 64 + (t >> 2)];
    const ushort_t* wb = wupT + (size_t)e * F_DIM * D_DIM + (size_t)(nb * BN) * D_DIM;

    float4v acc[4][4];
#pragma unroll
    for (int i = 0; i < 4; ++i)
#pragma unroll
        for (int j = 0; j < 4; ++j)
#pragma unroll
            for (int q = 0; q < 4; ++q) acc[i][j][q] = 0.f;

    int csw = (((t & 3) ^ ((t >> 3) & 3))) * 8;    // staged src chunk (swizzled)
    int swoff = (((lane >> 4) ^ (((lane & 15) >> 1) & 3))) * 8;  // read-side

    const ushort_t* gA0 = xb + (size_t)tokA0 * D_DIM + csw;
    const ushort_t* gA1 = xb + (size_t)tokA1 * D_DIM + csw;
    const ushort_t* gB0 = wb + (size_t)(t >> 2) * D_DIM + csw;
    const ushort_t* gB1 = wb + (size_t)(64 + (t >> 2)) * D_DIM + csw;

#define STAGE_UP(buf, kt) do { int k0 = (kt) * BK;                            \
        char* AsB = (char*)&As[buf][0][0]; char* BsB = (char*)&Bs[buf][0][0]; \
        GLOAD_LDS16(gA0 + k0, AsB + wave * 1024);                             \
        GLOAD_LDS16(gA1 + k0, AsB + 4096 + wave * 1024);                      \
        GLOAD_LDS16(gB0 + k0, BsB + wave * 1024);                             \
        GLOAD_LDS16(gB1 + k0, BsB + 4096 + wave * 1024); } while (0)

    STAGE_UP(0, 0);
    __syncthreads();
    const int nt = D_DIM / BK;
    for (int kt = 0; kt < nt; ++kt) {
        int buf = kt & 1;
        if (kt + 1 < nt) STAGE_UP(buf ^ 1, kt + 1);
        short8 af[4], bfr[4];
#pragma unroll
        for (int m = 0; m < 4; ++m)
            af[m] = *(const short8*)&As[buf][wm * 64 + m * 16 + (lane & 15)][swoff];
#pragma unroll
        for (int n = 0; n < 4; ++n)
            bfr[n] = *(const short8*)&Bs[buf][wn * 64 + n * 16 + (lane & 15)][swoff];
#pragma unroll
        for (int m = 0; m < 4; ++m)
#pragma unroll
            for (int n = 0; n < 4; ++n)
                acc[m][n] = __builtin_amdgcn_mfma_f32_16x16x32_bf16(af[m], bfr[n], acc[m][n], 0, 0, 0);
        __syncthreads();
    }

#pragma unroll
    for (int m = 0; m < 4; ++m) {
        int row_local = wm * 64 + m * 16 + (lane >> 4) * 4;
#pragma unroll
        for (int n = 0; n < 4; ++n) {
            int col = nb * BN + wn * 64 + n * 16 + (lane & 15);
            float bia = b_up[e * F_DIM + col];
#pragma unroll
            for (int j = 0; j < 4; ++j) {
                float v = acc[m][n][j] + bia;
                h[(size_t)(row0 + row_local + j) * F_DIM + col] = f2bf(gelu_fast(v));
            }
        }
    }
}

// ---------------------------------------------------------------- down GEMM
// 128x128 tile (16 MFMA/wave per K-step), split-K x2, bf16 partial planes
__global__ void k_down_gemm(const ushort_t* __restrict__ h, const ushort_t* __restrict__ wdT,
                            const float* __restrict__ b_down, const int* __restrict__ counts,
                            ushort_t* __restrict__ yb) {
    int wg = blockIdx.x;
    int lin = (wg & 7) * (DN_BLOCKS / 8) + (wg >> 3);
    int nbkc = lin / RBMAX;            // 0..11  (nb,kc)-outer
    int rb = lin % RBMAX;              // rb-inner: h rows hot per XCD chunk
    int nb = nbkc >> 1, kc = nbkc & 1;
    int total;
    int e = rb_expert(counts, rb, total);
    if (rb >= total) return;
    __shared__ __align__(16) ushort_t As[2][BM][BK];
    __shared__ __align__(16) ushort_t Bs[2][BN][BK];
    int t = threadIdx.x, wave = t >> 6, lane = t & 63;
    int wm = wave >> 1, wn = wave & 1;

    int row0 = rb * BM;
    int kbase = kc * KHALF;
    const ushort_t* ha = h + (size_t)row0 * F_DIM + kbase;
    const ushort_t* wb = wdT + (size_t)e * D_DIM * F_DIM + (size_t)(nb * BN) * F_DIM + kbase;

    float4v acc[4][4];
#pragma unroll
    for (int i = 0; i < 4; ++i)
#pragma unroll
        for (int j = 0; j < 4; ++j)
#pragma unroll
            for (int q = 0; q < 4; ++q) acc[i][j][q] = 0.f;

    int csw = (((t & 3) ^ ((t >> 3) & 3))) * 8;
    int swoff = (((lane >> 4) ^ (((lane & 15) >> 1) & 3))) * 8;

    const ushort_t* gA0 = ha + (size_t)(t >> 2) * F_DIM + csw;
    const ushort_t* gA1 = ha + (size_t)(64 + (t >> 2)) * F_DIM + csw;
    const ushort_t* gB0 = wb + (size_t)(t >> 2) * F_DIM + csw;
    const ushort_t* gB1 = wb + (size_t)(64 + (t >> 2)) * F_DIM + csw;

#define STAGE_DN(buf, kt) do { int k0 = (kt) * BK;                            \
        char* AsB = (char*)&As[buf][0][0]; char* BsB = (char*)&Bs[buf][0][0]; \
        GLOAD_LDS16(gA0 + k0, AsB + wave * 1024);                             \
        GLOAD_LDS16(gA1 + k0, AsB + 4096 + wave * 1024);                      \
        GLOAD_LDS16(gB0 + k0, BsB + wave * 1024);                             \
        GLOAD_LDS16(gB1 + k0, BsB + 4096 + wave * 1024); } while (0)

    STAGE_DN(0, 0);
    __syncthreads();
    const int nt = KHALF / BK;
    for (int kt = 0; kt < nt; ++kt) {
        int buf = kt & 1;
        if (kt + 1 < nt) STAGE_DN(buf ^ 1, kt + 1);
        short8 af[4], bfr[4];
#pragma unroll
        for (int m = 0; m < 4; ++m)
            af[m] = *(const short8*)&As[buf][wm * 64 + m * 16 + (lane & 15)][swoff];
#pragma unroll
        for (int n = 0; n < 4; ++n)
            bfr[n] = *(const short8*)&Bs[buf][wn * 64 + n * 16 + (lane & 15)][swoff];
#pragma unroll
        for (int m = 0; m < 4; ++m)
#pragma unroll
            for (int n = 0; n < 4; ++n)
                acc[m][n] = __builtin_amdgcn_mfma_f32_16x16x32_bf16(af[m], bfr[n], acc[m][n], 0, 0, 0);
        __syncthreads();
    }

    ushort_t* ybk = yb + (size_t)kc * GROWS * D_DIM;
#pragma unroll
    for (int m = 0; m < 4; ++m) {
        int row_local = wm * 64 + m * 16 + (lane >> 4) * 4;
#pragma unroll
        for (int n = 0; n < 4; ++n) {
            int col = nb * BN + wn * 64 + n * 16 + (lane & 15);
            float bia = (kc == 0) ? b_down[e * D_DIM + col] : 0.f;
#pragma unroll
            for (int j = 0; j < 4; ++j) {
                ybk[(size_t)(row0 + row_local + j) * D_DIM + col] =
                    f2bf(acc[m][n][j] + bia);
            }
        }
    }
}

// ---------------------------------------------------------------- combine
// out[t] = w0*(y[0][g0]+y[1][g0]) + w1*(y[0][g1]+y[1][g1])
__global__ void k_combine(const ushort_t* __restrict__ yb, const int* __restrict__ rowOf,
                          const float* __restrict__ wsel, float* __restrict__ out) {
    int wave = threadIdx.x >> 6, lane = threadIdx.x & 63;
    int t = blockIdx.x * 4 + wave;
    int g0 = rowOf[t * 2], g1 = rowOf[t * 2 + 1];
    float w0 = wsel[t * 2], w1 = wsel[t * 2 + 1];
    const ushort_t* a0 = yb + (size_t)g0 * D_DIM;
    const ushort_t* a1 = yb + ((size_t)GROWS + g0) * D_DIM;
    const ushort_t* b0 = yb + (size_t)g1 * D_DIM;
    const ushort_t* b1 = yb + ((size_t)GROWS + g1) * D_DIM;
    float4v* o = (float4v*)(out + (size_t)t * D_DIM);
#pragma unroll
    for (int i = 0; i < 3; ++i) {
        int idx = (lane + i * 64) * 4;
        short4v va0 = *(const short4v*)&a0[idx];
        short4v va1 = *(const short4v*)&a1[idx];
        short4v vb0 = *(const short4v*)&b0[idx];
        short4v vb1 = *(const short4v*)&b1[idx];
        float4v r;
#pragma unroll
        for (int q = 0; q < 4; ++q)
            r[q] = w0 * (bf2f((ushort_t)va0[q]) + bf2f((ushort_t)va1[q]))
                 + w1 * (bf2f((ushort_t)vb0[q]) + bf2f((ushort_t)vb1[q]));
        o[(lane + i * 64)] = r;
    }
}

// ---------------------------------------------------------------- launch
extern "C" void kernel_launch(void* const* d_in, const int* in_sizes, int n_in,
                              void* d_out, int out_size, void* d_ws, size_t ws_size,
                              hipStream_t stream) {
    const float* x   = (const float*)d_in[0];   // [2,2048,768]
    const float* gw  = (const float*)d_in[1];   // [768,8]
    const float* wup = (const float*)d_in[2];   // [8,768,3072]
    const float* bup = (const float*)d_in[3];   // [8,3072]
    const float* wdn = (const float*)d_in[4];   // [8,3072,768]
    const float* bdn = (const float*)d_in[5];   // [8,768]
    float* out = (float*)d_out;

    char* ws = (char*)d_ws;
    int*   counts = (int*)(ws);
    int*   list   = (int*)(ws + 1024);
    size_t p = 1024 + (size_t)E_NUM * T_TOKENS * 4;
    int*   clist  = (int*)(ws + p); p += (size_t)GROWS * 4;
    int*   rowOf  = (int*)(ws + p); p += (size_t)T_TOKENS * 2 * 4;
    float* wsel   = (float*)(ws + p); p += (size_t)T_TOKENS * 2 * 4;
    p = (p + 255) & ~(size_t)255;
    size_t p_xb = p;
    ushort_t* xb   = (ushort_t*)(ws + p); p += (size_t)T_TOKENS * D_DIM * 2;
    ushort_t* wupT = (ushort_t*)(ws + p); p += (size_t)E_NUM * D_DIM * F_DIM * 2;
    ushort_t* wdnT = (ushort_t*)(ws + p); p += (size_t)E_NUM * D_DIM * F_DIM * 2;
    ushort_t* hbuf = (ushort_t*)(ws + p); p += (size_t)GROWS * F_DIM * 2;
    // ybuf (2 planes bf16, 28.3MB) aliases xb+wupT (44MB, dead after up GEMM)
    ushort_t* ybuf = (ushort_t*)(ws + p_xb);

    hipMemsetAsync(counts, 0, E_NUM * sizeof(int), stream);
    k_gate<<<T_TOKENS / 16, 1024, 0, stream>>>(x, gw, counts, list, wsel, xb);
    k_trans<<<TRT_TOT / 4, 256, 0, stream>>>(wup, wdn, wupT, wdnT);
    k_compact<<<dim3(17, E_NUM), 256, 0, stream>>>(counts, list, clist, rowOf);
    k_up_gemm<<<UP_BLOCKS, 256, 0, stream>>>(xb, wupT, bup, counts, clist, hbuf);
    k_down_gemm<<<DN_BLOCKS, 256, 0, stream>>>(hbuf, wdnT, bdn, counts, ybuf);
    k_combine<<<T_TOKENS / 4, 256, 0, stream>>>(ybuf, rowOf, wsel, out);
}

// Round 12
// 204.283 us; speedup vs baseline: 2.0675x; 1.0979x over previous
//
#include <hip/hip_runtime.h>
#include <hip/hip_bf16.h>
#include <math.h>

// Problem constants (B=2,S=2048 -> T=4096 tokens)
#define T_TOKENS 4096
#define D_DIM 768
#define F_DIM 3072
#define E_NUM 8

#define BM 128
#define BN 128
#define BK 32
#define RBMAX 72                 // max padded 128-row blocks
#define NBU (F_DIM / BN)         // 24
#define NBD (D_DIM / BN)         // 6
#define UP_BLOCKS (NBU * RBMAX)  // 1728
#define KHALF (F_DIM / 2)        // 1536: down split-K chunk
#define DN_BLOCKS (NBD * RBMAX * 2)  // 864 (rb outer x (nb,kc) inner)
#define GROWS (RBMAX * BM)       // 9216 padded rows

#define TILE_LDS (64 * 66)       // bf16 elems per wave-private transpose tile
#define TRT_WUP 4608             // 64x64 tiles in wup
#define TRT_TOT 9216             // + wdn

typedef __attribute__((ext_vector_type(8))) short short8;
typedef __attribute__((ext_vector_type(4))) short short4v;
typedef __attribute__((ext_vector_type(4))) float float4v;
typedef unsigned short ushort_t;
typedef unsigned long long ull_t;

__device__ __forceinline__ ushort_t f2bf(float f) {
    union { float f; unsigned u; } v; v.f = f;
    unsigned r = v.u + 0x7fffu + ((v.u >> 16) & 1u);   // RNE
    return (ushort_t)(r >> 16);
}

__device__ __forceinline__ float bf2f(ushort_t u) {
    union { unsigned u; float f; } v; v.u = ((unsigned)u) << 16;
    return v.f;
}

__device__ __forceinline__ float gelu_fast(float v) {
    float u = v + 0.044715f * v * v * v;
    return v / (1.f + __expf(-1.5957691216f * u));
}

#define GLOAD_LDS16(gp, lp) __builtin_amdgcn_global_load_lds( \
    (const __attribute__((address_space(1))) void*)(gp),      \
    (__attribute__((address_space(3))) void*)(lp), 16, 0, 0)

// expert for padded 128-row block rb, plus total block count
__device__ __forceinline__ int rb_expert(const int* __restrict__ counts,
                                         int rb, int& total) {
    int e = 0, acc = 0;
#pragma unroll
    for (int ee = 0; ee < E_NUM; ++ee) {
        int nbe = (counts[ee] + BM - 1) / BM;
        if (rb >= acc && rb < acc + nbe) e = ee;
        acc += nbe;
    }
    total = acc;
    return e;
}

// ---------------------------------------------------------------- tile coords
__device__ __forceinline__ void tile_coords(int g, int R, int C,
                                            int& e, int& r0, int& c0) {
    int tpr = C / 64, tpc = R / 64;
    e = g / (tpr * tpc);
    int rem = g % (tpr * tpc);
    r0 = (rem / tpr) * 64;
    c0 = (rem % tpr) * 64;
}

// ------------------------------------------------- per-WAVE barrier-free transpose
__device__ __forceinline__ void wave_transpose64(const float* __restrict__ ip,
                                                 ushort_t* __restrict__ op,
                                                 int R, int C, int r0, int c0,
                                                 ushort_t* __restrict__ tl) {
    int l = threadIdx.x & 63;
    int lr = l >> 4;             // 0..3
    int lc4 = (l & 15) * 4;      // 0,4,...,60

    float4v v[16];
#pragma unroll
    for (int i = 0; i < 16; ++i)
        v[i] = *(const float4v*)&ip[(size_t)(r0 + 4 * i + lr) * C + c0 + lc4];
#pragma unroll
    for (int i = 0; i < 16; ++i) {
        short4v s = { (short)f2bf(v[i][0]), (short)f2bf(v[i][1]),
                      (short)f2bf(v[i][2]), (short)f2bf(v[i][3]) };
        *(short4v*)&tl[(4 * i + lr) * 66 + lc4] = s;
    }
    asm volatile("s_waitcnt lgkmcnt(0)" ::: "memory");
#pragma unroll
    for (int i = 0; i < 16; ++i) {
        int rr = 4 * i + lr;                     // output row (= orig col c0+rr)
        short4v s = { (short)tl[(lc4 + 0) * 66 + rr],
                      (short)tl[(lc4 + 1) * 66 + rr],
                      (short)tl[(lc4 + 2) * 66 + rr],
                      (short)tl[(lc4 + 3) * 66 + rr] };
        *(short4v*)&op[(size_t)(c0 + rr) * R + r0 + lc4] = s;
    }
}

// ---------------------------------------------------------------- transpose kernel
__global__ __launch_bounds__(256) void k_trans(const float* __restrict__ wup,
                                               const float* __restrict__ wdn,
                                               ushort_t* __restrict__ wupT,
                                               ushort_t* __restrict__ wdnT) {
    __shared__ ushort_t ttile[4][TILE_LDS];
    int wave = threadIdx.x >> 6;
    int g = blockIdx.x * 4 + wave;               // 0..9215
    const float* in; ushort_t* outp; int R, C;
    if (g < TRT_WUP) { in = wup; outp = wupT; R = D_DIM; C = F_DIM; }
    else { g -= TRT_WUP; in = wdn; outp = wdnT; R = F_DIM; C = D_DIM; }
    int e, r0, c0;
    tile_coords(g, R, C, e, r0, c0);
    wave_transpose64(in + (size_t)e * R * C, outp + (size_t)e * R * C,
                     R, C, r0, c0, &ttile[wave][0]);
}

// ---------------------------------------------------------------- gate (+ x->bf16)
__global__ __launch_bounds__(1024) void k_gate(const float* __restrict__ x,
                                               const float* __restrict__ gw,
                                               int* __restrict__ counts,
                                               int* __restrict__ list,
                                               float* __restrict__ wsel,
                                               ushort_t* __restrict__ xb) {
    __shared__ int hist[E_NUM];
    __shared__ int base[E_NUM];
    int wave = threadIdx.x >> 6, lane = threadIdx.x & 63;
    int t = blockIdx.x * 16 + wave;

    float acc[E_NUM];
#pragma unroll
    for (int e = 0; e < E_NUM; ++e) acc[e] = 0.f;
    const float4v* xr4 = (const float4v*)(x + (size_t)t * D_DIM);
    ull_t* xbr = (ull_t*)(xb + (size_t)t * D_DIM);
#pragma unroll
    for (int i = 0; i < 3; ++i) {
        int j = lane + i * 64;                   // float4 index within row
        float4v v = xr4[j];
        xbr[j] = (ull_t)f2bf(v[0]) | ((ull_t)f2bf(v[1]) << 16) |
                 ((ull_t)f2bf(v[2]) << 32) | ((ull_t)f2bf(v[3]) << 48);
        int d0 = 4 * j;
#pragma unroll
        for (int q = 0; q < 4; ++q) {
            const float* g = gw + (size_t)(d0 + q) * E_NUM;
#pragma unroll
            for (int e = 0; e < E_NUM; ++e) acc[e] += v[q] * g[e];
        }
    }
#pragma unroll
    for (int e = 0; e < E_NUM; ++e) {
#pragma unroll
        for (int s = 32; s >= 1; s >>= 1) acc[e] += __shfl_xor(acc[e], s);
    }

    if (threadIdx.x < E_NUM) hist[threadIdx.x] = 0;
    __syncthreads();

    int e1 = 0, e2 = 0, s1 = 0, s2 = 0;
    if (lane == 0) {
        float mx = acc[0];
#pragma unroll
        for (int e = 1; e < E_NUM; ++e) mx = fmaxf(mx, acc[e]);
        float p[E_NUM], sum = 0.f;
#pragma unroll
        for (int e = 0; e < E_NUM; ++e) { p[e] = expf(acc[e] - mx); sum += p[e]; }
        float inv = 1.f / sum;
#pragma unroll
        for (int e = 0; e < E_NUM; ++e) p[e] *= inv;
#pragma unroll
        for (int e = 1; e < E_NUM; ++e) if (p[e] > p[e1]) e1 = e;
        e2 = (e1 == 0) ? 1 : 0;
#pragma unroll
        for (int e = 0; e < E_NUM; ++e) if (e != e1 && p[e] > p[e2]) e2 = e;
        s1 = atomicAdd(&hist[e1], 1);            // LDS atomic
        s2 = atomicAdd(&hist[e2], 1);
        wsel[t * 2 + 0] = p[e1];
        wsel[t * 2 + 1] = p[e2];
    }
    __syncthreads();
    if (threadIdx.x < E_NUM)
        base[threadIdx.x] = atomicAdd(&counts[threadIdx.x], hist[threadIdx.x]);
    __syncthreads();
    if (lane == 0) {
        list[e1 * T_TOKENS + base[e1] + s1] = t * 2 + 0;   // token | slot bit
        list[e2 * T_TOKENS + base[e2] + s2] = t * 2 + 1;
    }
}

// ---------------------------------------------------------------- compact
__global__ void k_compact(const int* __restrict__ counts, const int* __restrict__ list,
                          int* __restrict__ clist, int* __restrict__ rowOf) {
    int e = blockIdx.y;
    int s = blockIdx.x * 256 + threadIdx.x;
    int off = 0, cnt = 0;
#pragma unroll
    for (int ee = 0; ee < E_NUM; ++ee) {
        int c = counts[ee];
        int pc = (c + BM - 1) / BM * BM;
        if (ee < e) off += pc;
        if (ee == e) cnt = c;
    }
    int pcnt = (cnt + BM - 1) / BM * BM;
    if (s >= pcnt) return;
    int g = off + s;
    if (s < cnt) {
        int v = list[e * T_TOKENS + s];
        clist[g] = v >> 1;
        rowOf[v] = g;                 // v = tok*2 + slot
    } else {
        clist[g] = 0;                 // padding row gathers token 0 (output unused)
    }
}

// ---------------------------------------------------------------- up GEMM
// rb-outer / nb-inner per XCD chunk: A tile L2-resident across 24 nb reuses
__global__ void k_up_gemm(const ushort_t* __restrict__ xb, const ushort_t* __restrict__ wupT,
                          const float* __restrict__ b_up, const int* __restrict__ counts,
                          const int* __restrict__ clist, ushort_t* __restrict__ h) {
    int wg = blockIdx.x;
    int lin = (wg & 7) * (UP_BLOCKS / 8) + (wg >> 3);
    int nb = lin % NBU;
    int rb = lin / NBU;
    int total;
    int e = rb_expert(counts, rb, total);
    if (rb >= total) return;
    __shared__ __align__(16) ushort_t As[2][BM][BK];
    __shared__ __align__(16) ushort_t Bs[2][BN][BK];
    int t = threadIdx.x, wave = t >> 6, lane = t & 63;
    int wm = wave >> 1, wn = wave & 1;

    int row0 = rb * BM;
    int tokA0 = clist[row0 + (t >> 2)];
    int tokA1 = clist[row0 + 64 + (t >> 2)];
    const ushort_t* wb = wupT + (size_t)e * F_DIM * D_DIM + (size_t)(nb * BN) * D_DIM;

    float4v acc[4][4];
#pragma unroll
    for (int i = 0; i < 4; ++i)
#pragma unroll
        for (int j = 0; j < 4; ++j)
#pragma unroll
            for (int q = 0; q < 4; ++q) acc[i][j][q] = 0.f;

    int csw = (((t & 3) ^ ((t >> 3) & 3))) * 8;    // staged src chunk (swizzled)
    int swoff = (((lane >> 4) ^ (((lane & 15) >> 1) & 3))) * 8;  // read-side

    const ushort_t* gA0 = xb + (size_t)tokA0 * D_DIM + csw;
    const ushort_t* gA1 = xb + (size_t)tokA1 * D_DIM + csw;
    const ushort_t* gB0 = wb + (size_t)(t >> 2) * D_DIM + csw;
    const ushort_t* gB1 = wb + (size_t)(64 + (t >> 2)) * D_DIM + csw;

#define STAGE_UP(buf, kt) do { int k0 = (kt) * BK;                            \
        char* AsB = (char*)&As[buf][0][0]; char* BsB = (char*)&Bs[buf][0][0]; \
        GLOAD_LDS16(gA0 + k0, AsB + wave * 1024);                             \
        GLOAD_LDS16(gA1 + k0, AsB + 4096 + wave * 1024);                      \
        GLOAD_LDS16(gB0 + k0, BsB + wave * 1024);                             \
        GLOAD_LDS16(gB1 + k0, BsB + 4096 + wave * 1024); } while (0)

    STAGE_UP(0, 0);
    __syncthreads();
    const int nt = D_DIM / BK;
    for (int kt = 0; kt < nt; ++kt) {
        int buf = kt & 1;
        if (kt + 1 < nt) STAGE_UP(buf ^ 1, kt + 1);
        short8 af[4], bfr[4];
#pragma unroll
        for (int m = 0; m < 4; ++m)
            af[m] = *(const short8*)&As[buf][wm * 64 + m * 16 + (lane & 15)][swoff];
#pragma unroll
        for (int n = 0; n < 4; ++n)
            bfr[n] = *(const short8*)&Bs[buf][wn * 64 + n * 16 + (lane & 15)][swoff];
#pragma unroll
        for (int m = 0; m < 4; ++m)
#pragma unroll
            for (int n = 0; n < 4; ++n)
                acc[m][n] = __builtin_amdgcn_mfma_f32_16x16x32_bf16(af[m], bfr[n], acc[m][n], 0, 0, 0);
        __syncthreads();
    }

#pragma unroll
    for (int m = 0; m < 4; ++m) {
        int row_local = wm * 64 + m * 16 + (lane >> 4) * 4;
#pragma unroll
        for (int n = 0; n < 4; ++n) {
            int col = nb * BN + wn * 64 + n * 16 + (lane & 15);
            float bia = b_up[e * F_DIM + col];
#pragma unroll
            for (int j = 0; j < 4; ++j) {
                float v = acc[m][n][j] + bia;
                h[(size_t)(row0 + row_local + j) * F_DIM + col] = f2bf(gelu_fast(v));
            }
        }
    }
}

// ---------------------------------------------------------------- down GEMM
// rb-outer / (nb,kc)-inner per XCD chunk: h tile read once into L2, reused 12x
__global__ void k_down_gemm(const ushort_t* __restrict__ h, const ushort_t* __restrict__ wdT,
                            const float* __restrict__ b_down, const int* __restrict__ counts,
                            ushort_t* __restrict__ yb) {
    int wg = blockIdx.x;
    int lin = (wg & 7) * (DN_BLOCKS / 8) + (wg >> 3);
    int nbkc = lin % (NBD * 2);        // 0..11 inner
    int rb = lin / (NBD * 2);          // rb outer: A tile hot in L2 per XCD
    int nb = nbkc >> 1, kc = nbkc & 1;
    int total;
    int e = rb_expert(counts, rb, total);
    if (rb >= total) return;
    __shared__ __align__(16) ushort_t As[2][BM][BK];
    __shared__ __align__(16) ushort_t Bs[2][BN][BK];
    int t = threadIdx.x, wave = t >> 6, lane = t & 63;
    int wm = wave >> 1, wn = wave & 1;

    int row0 = rb * BM;
    int kbase = kc * KHALF;
    const ushort_t* ha = h + (size_t)row0 * F_DIM + kbase;
    const ushort_t* wb = wdT + (size_t)e * D_DIM * F_DIM + (size_t)(nb * BN) * F_DIM + kbase;

    float4v acc[4][4];
#pragma unroll
    for (int i = 0; i < 4; ++i)
#pragma unroll
        for (int j = 0; j < 4; ++j)
#pragma unroll
            for (int q = 0; q < 4; ++q) acc[i][j][q] = 0.f;

    int csw = (((t & 3) ^ ((t >> 3) & 3))) * 8;
    int swoff = (((lane >> 4) ^ (((lane & 15) >> 1) & 3))) * 8;

    const ushort_t* gA0 = ha + (size_t)(t >> 2) * F_DIM + csw;
    const ushort_t* gA1 = ha + (size_t)(64 + (t >> 2)) * F_DIM + csw;
    const ushort_t* gB0 = wb + (size_t)(t >> 2) * F_DIM + csw;
    const ushort_t* gB1 = wb + (size_t)(64 + (t >> 2)) * F_DIM + csw;

#define STAGE_DN(buf, kt) do { int k0 = (kt) * BK;                            \
        char* AsB = (char*)&As[buf][0][0]; char* BsB = (char*)&Bs[buf][0][0]; \
        GLOAD_LDS16(gA0 + k0, AsB + wave * 1024);                             \
        GLOAD_LDS16(gA1 + k0, AsB + 4096 + wave * 1024);                      \
        GLOAD_LDS16(gB0 + k0, BsB + wave * 1024);                             \
        GLOAD_LDS16(gB1 + k0, BsB + 4096 + wave * 1024); } while (0)

    STAGE_DN(0, 0);
    __syncthreads();
    const int nt = KHALF / BK;
    for (int kt = 0; kt < nt; ++kt) {
        int buf = kt & 1;
        if (kt + 1 < nt) STAGE_DN(buf ^ 1, kt + 1);
        short8 af[4], bfr[4];
#pragma unroll
        for (int m = 0; m < 4; ++m)
            af[m] = *(const short8*)&As[buf][wm * 64 + m * 16 + (lane & 15)][swoff];
#pragma unroll
        for (int n = 0; n < 4; ++n)
            bfr[n] = *(const short8*)&Bs[buf][wn * 64 + n * 16 + (lane & 15)][swoff];
#pragma unroll
        for (int m = 0; m < 4; ++m)
#pragma unroll
            for (int n = 0; n < 4; ++n)
                acc[m][n] = __builtin_amdgcn_mfma_f32_16x16x32_bf16(af[m], bfr[n], acc[m][n], 0, 0, 0);
        __syncthreads();
    }

    ushort_t* ybk = yb + (size_t)kc * GROWS * D_DIM;
#pragma unroll
    for (int m = 0; m < 4; ++m) {
        int row_local = wm * 64 + m * 16 + (lane >> 4) * 4;
#pragma unroll
        for (int n = 0; n < 4; ++n) {
            int col = nb * BN + wn * 64 + n * 16 + (lane & 15);
            float bia = (kc == 0) ? b_down[e * D_DIM + col] : 0.f;
#pragma unroll
            for (int j = 0; j < 4; ++j) {
                ybk[(size_t)(row0 + row_local + j) * D_DIM + col] =
                    f2bf(acc[m][n][j] + bia);
            }
        }
    }
}

// ---------------------------------------------------------------- combine
// out[t] = w0*(y[0][g0]+y[1][g0]) + w1*(y[0][g1]+y[1][g1])
__global__ void k_combine(const ushort_t* __restrict__ yb, const int* __restrict__ rowOf,
                          const float* __restrict__ wsel, float* __restrict__ out) {
    int wave = threadIdx.x >> 6, lane = threadIdx.x & 63;
    int t = blockIdx.x * 4 + wave;
    int g0 = rowOf[t * 2], g1 = rowOf[t * 2 + 1];
    float w0 = wsel[t * 2], w1 = wsel[t * 2 + 1];
    const ushort_t* a0 = yb + (size_t)g0 * D_DIM;
    const ushort_t* a1 = yb + ((size_t)GROWS + g0) * D_DIM;
    const ushort_t* b0 = yb + (size_t)g1 * D_DIM;
    const ushort_t* b1 = yb + ((size_t)GROWS + g1) * D_DIM;
    float4v* o = (float4v*)(out + (size_t)t * D_DIM);
#pragma unroll
    for (int i = 0; i < 3; ++i) {
        int idx = (lane + i * 64) * 4;
        short4v va0 = *(const short4v*)&a0[idx];
        short4v va1 = *(const short4v*)&a1[idx];
        short4v vb0 = *(const short4v*)&b0[idx];
        short4v vb1 = *(const short4v*)&b1[idx];
        float4v r;
#pragma unroll
        for (int q = 0; q < 4; ++q)
            r[q] = w0 * (bf2f((ushort_t)va0[q]) + bf2f((ushort_t)va1[q]))
                 + w1 * (bf2f((ushort_t)vb0[q]) + bf2f((ushort_t)vb1[q]));
        o[(lane + i * 64)] = r;
    }
}

// ---------------------------------------------------------------- launch
extern "C" void kernel_launch(void* const* d_in, const int* in_sizes, int n_in,
                              void* d_out, int out_size, void* d_ws, size_t ws_size,
                              hipStream_t stream) {
    const float* x   = (const float*)d_in[0];   // [2,2048,768]
    const float* gw  = (const float*)d_in[1];   // [768,8]
    const float* wup = (const float*)d_in[2];   // [8,768,3072]
    const float* bup = (const float*)d_in[3];   // [8,3072]
    const float* wdn = (const float*)d_in[4];   // [8,3072,768]
    const float* bdn = (const float*)d_in[5];   // [8,768]
    float* out = (float*)d_out;

    char* ws = (char*)d_ws;
    int*   counts = (int*)(ws);
    int*   list   = (int*)(ws + 1024);
    size_t p = 1024 + (size_t)E_NUM * T_TOKENS * 4;
    int*   clist  = (int*)(ws + p); p += (size_t)GROWS * 4;
    int*   rowOf  = (int*)(ws + p); p += (size_t)T_TOKENS * 2 * 4;
    float* wsel   = (float*)(ws + p); p += (size_t)T_TOKENS * 2 * 4;
    p = (p + 255) & ~(size_t)255;
    size_t p_xb = p;
    ushort_t* xb   = (ushort_t*)(ws + p); p += (size_t)T_TOKENS * D_DIM * 2;
    ushort_t* wupT = (ushort_t*)(ws + p); p += (size_t)E_NUM * D_DIM * F_DIM * 2;
    ushort_t* wdnT = (ushort_t*)(ws + p); p += (size_t)E_NUM * D_DIM * F_DIM * 2;
    ushort_t* hbuf = (ushort_t*)(ws + p); p += (size_t)GROWS * F_DIM * 2;
    // ybuf (2 planes bf16, 28.3MB) aliases xb+wupT (44MB, dead after up GEMM)
    ushort_t* ybuf = (ushort_t*)(ws + p_xb);

    hipMemsetAsync(counts, 0, E_NUM * sizeof(int), stream);
    k_gate<<<T_TOKENS / 16, 1024, 0, stream>>>(x, gw, counts, list, wsel, xb);
    k_trans<<<TRT_TOT / 4, 256, 0, stream>>>(wup, wdn, wupT, wdnT);
    k_compact<<<dim3(17, E_NUM), 256, 0, stream>>>(counts, list, clist, rowOf);
    k_up_gemm<<<UP_BLOCKS, 256, 0, stream>>>(xb, wupT, bup, counts, clist, hbuf);
    k_down_gemm<<<DN_BLOCKS, 256, 0, stream>>>(hbuf, wdnT, bdn, counts, ybuf);
    k_combine<<<T_TOKENS / 4, 256, 0, stream>>>(ybuf, rowOf, wsel, out);
}